// Round 3
// baseline (463.935 us; speedup 1.0000x reference)
//
#include <hip/hip_runtime.h>
#include <math.h>

#define T 8
#define N 5000
#define E 160000
#define EN (E + N)
#define IN_DIM 64
#define HID 128
#define H 8
#define D 16
#define NC 2
#define MT 32            // rows per tiled-GEMM block

__device__ __forceinline__ float leaky(float e) { return (e >= 0.0f) ? e : 0.2f * e; }

// fused h=relu(x@Wp+bp); xh=h@Wg; a_s/a_d coef epilogue. Also zeroes cursor.
__global__ __launch_bounds__(256) void k_pg(const float* __restrict__ x,
                                            const float* __restrict__ Wp,
                                            const float* __restrict__ bp,
                                            const float* __restrict__ Wg,
                                            const float* __restrict__ asrc,
                                            const float* __restrict__ adst,
                                            float* __restrict__ xh,
                                            float* __restrict__ a_s,
                                            float* __restrict__ a_d,
                                            int* __restrict__ cursor) {
    __shared__ float xt[MT][IN_DIM];
    __shared__ float ht[MT][HID + 1];
    int row0 = blockIdx.x * MT;
    int tid = threadIdx.x;

    {   // fold the cursor memset into this kernel (runs before k_hist)
        int gi = blockIdx.x * 256 + tid;
        if (gi < T * N) cursor[gi] = 0;
    }

    for (int idx = tid; idx < MT * IN_DIM; idx += 256) {
        int r = idx >> 6, k = idx & 63;
        xt[r][k] = x[(size_t)(row0 + r) * IN_DIM + k];
    }
    __syncthreads();

    int cg = tid & 31;
    int rg = tid >> 5;
    int c0 = cg * 4, r0 = rg * 4;

    {
        float4 b4 = *(const float4*)(bp + c0);
        float a00=b4.x,a01=b4.y,a02=b4.z,a03=b4.w;
        float a10=b4.x,a11=b4.y,a12=b4.z,a13=b4.w;
        float a20=b4.x,a21=b4.y,a22=b4.z,a23=b4.w;
        float a30=b4.x,a31=b4.y,a32=b4.z,a33=b4.w;
        for (int k = 0; k < IN_DIM; ++k) {
            float4 w = *(const float4*)(Wp + (size_t)k * HID + c0);
            float x0 = xt[r0 + 0][k], x1 = xt[r0 + 1][k];
            float x2 = xt[r0 + 2][k], x3 = xt[r0 + 3][k];
            a00 += x0*w.x; a01 += x0*w.y; a02 += x0*w.z; a03 += x0*w.w;
            a10 += x1*w.x; a11 += x1*w.y; a12 += x1*w.z; a13 += x1*w.w;
            a20 += x2*w.x; a21 += x2*w.y; a22 += x2*w.z; a23 += x2*w.w;
            a30 += x3*w.x; a31 += x3*w.y; a32 += x3*w.z; a33 += x3*w.w;
        }
        ht[r0+0][c0+0]=fmaxf(a00,0.f); ht[r0+0][c0+1]=fmaxf(a01,0.f);
        ht[r0+0][c0+2]=fmaxf(a02,0.f); ht[r0+0][c0+3]=fmaxf(a03,0.f);
        ht[r0+1][c0+0]=fmaxf(a10,0.f); ht[r0+1][c0+1]=fmaxf(a11,0.f);
        ht[r0+1][c0+2]=fmaxf(a12,0.f); ht[r0+1][c0+3]=fmaxf(a13,0.f);
        ht[r0+2][c0+0]=fmaxf(a20,0.f); ht[r0+2][c0+1]=fmaxf(a21,0.f);
        ht[r0+2][c0+2]=fmaxf(a22,0.f); ht[r0+2][c0+3]=fmaxf(a23,0.f);
        ht[r0+3][c0+0]=fmaxf(a30,0.f); ht[r0+3][c0+1]=fmaxf(a31,0.f);
        ht[r0+3][c0+2]=fmaxf(a32,0.f); ht[r0+3][c0+3]=fmaxf(a33,0.f);
    }
    __syncthreads();

    float a00=0,a01=0,a02=0,a03=0, a10=0,a11=0,a12=0,a13=0;
    float a20=0,a21=0,a22=0,a23=0, a30=0,a31=0,a32=0,a33=0;
    for (int k = 0; k < HID; ++k) {
        float4 w = *(const float4*)(Wg + (size_t)k * HID + c0);
        float h0 = ht[r0 + 0][k], h1 = ht[r0 + 1][k];
        float h2 = ht[r0 + 2][k], h3 = ht[r0 + 3][k];
        a00 += h0*w.x; a01 += h0*w.y; a02 += h0*w.z; a03 += h0*w.w;
        a10 += h1*w.x; a11 += h1*w.y; a12 += h1*w.z; a13 += h1*w.w;
        a20 += h2*w.x; a21 += h2*w.y; a22 += h2*w.z; a23 += h2*w.w;
        a30 += h3*w.x; a31 += h3*w.y; a32 += h3*w.z; a33 += h3*w.w;
    }
    {
        float4 v;
        v.x=a00; v.y=a01; v.z=a02; v.w=a03;
        *(float4*)(xh + (size_t)(row0 + r0 + 0) * HID + c0) = v;
        v.x=a10; v.y=a11; v.z=a12; v.w=a13;
        *(float4*)(xh + (size_t)(row0 + r0 + 1) * HID + c0) = v;
        v.x=a20; v.y=a21; v.z=a22; v.w=a23;
        *(float4*)(xh + (size_t)(row0 + r0 + 2) * HID + c0) = v;
        v.x=a30; v.y=a31; v.z=a32; v.w=a33;
        *(float4*)(xh + (size_t)(row0 + r0 + 3) * HID + c0) = v;
    }
    __syncthreads();
    ht[r0+0][c0+0]=a00; ht[r0+0][c0+1]=a01; ht[r0+0][c0+2]=a02; ht[r0+0][c0+3]=a03;
    ht[r0+1][c0+0]=a10; ht[r0+1][c0+1]=a11; ht[r0+1][c0+2]=a12; ht[r0+1][c0+3]=a13;
    ht[r0+2][c0+0]=a20; ht[r0+2][c0+1]=a21; ht[r0+2][c0+2]=a22; ht[r0+2][c0+3]=a23;
    ht[r0+3][c0+0]=a30; ht[r0+3][c0+1]=a31; ht[r0+3][c0+2]=a32; ht[r0+3][c0+3]=a33;
    __syncthreads();

    {
        int r = tid >> 3, hh = tid & 7;
        float s1 = 0.0f, s2 = 0.0f;
        #pragma unroll
        for (int d = 0; d < D; ++d) {
            float v = ht[r][hh * D + d];
            s1 += v * asrc[hh * D + d];
            s2 += v * adst[hh * D + d];
        }
        a_s[(size_t)(row0 + r) * H + hh] = s1;
        a_d[(size_t)(row0 + r) * H + hh] = s2;
    }
}

// transpose W_qkv (384x128 -> 128x384) and W_o (128x128 -> 128x128)
__global__ void k_tr(const float* __restrict__ W_qkv, const float* __restrict__ W_o,
                     float* __restrict__ WTq, float* __restrict__ WoT) {
    int idx = blockIdx.x * 256 + threadIdx.x;
    if (idx < 384 * 128) {
        int j = idx >> 7, c = idx & 127;
        WTq[c * 384 + j] = W_qkv[idx];
    } else if (idx < 384 * 128 + 128 * 128) {
        int r = idx - 384 * 128;
        int j = r >> 7, k = r & 127;
        WoT[k * 128 + j] = W_o[r];
    }
}

__device__ __forceinline__ void esd_g(const int* __restrict__ ei, int t, int i,
                                      int& s, int& d) {
    if (i < E) {
        s = ei[(size_t)(2 * t) * E + i];
        d = ei[(size_t)(2 * t + 1) * E + i];
    } else {
        s = d = i - E;
    }
}

__global__ void k_hist(const int* __restrict__ ei, int* __restrict__ cursor) {
    int idx = blockIdx.x * 256 + threadIdx.x;
    if (idx >= T * EN) return;
    int t = idx / EN;
    int i = idx - t * EN;
    int s, d;
    esd_g(ei, t, i, s, d);
    atomicAdd(&cursor[t * N + d], 1);
}

__global__ void k_scan(int* __restrict__ cursor, int* __restrict__ offs) {
    __shared__ int part[256];
    int t = blockIdx.x;
    int tid = threadIdx.x;
    const int CH = 20;
    int begin = tid * CH;
    int sum = 0;
    for (int k = 0; k < CH; ++k) {
        int i = begin + k;
        if (i < N) sum += cursor[t * N + i];
    }
    part[tid] = sum;
    __syncthreads();
    if (tid == 0) {
        int run = 0;
        for (int i = 0; i < 256; ++i) { int v = part[i]; part[i] = run; run += v; }
        offs[t * (N + 1) + N] = run;
    }
    __syncthreads();
    int run = part[tid];
    for (int k = 0; k < CH; ++k) {
        int i = begin + k;
        if (i < N) {
            int cnt = cursor[t * N + i];
            offs[t * (N + 1) + i] = run;
            cursor[t * N + i] = run;
            run += cnt;
        }
    }
}

__global__ void k_scatter(const int* __restrict__ ei, int* __restrict__ cursor,
                          int* __restrict__ csr_src) {
    int idx = blockIdx.x * 256 + threadIdx.x;
    if (idx >= T * EN) return;
    int t = idx / EN;
    int i = idx - t * EN;
    int s, d;
    esd_g(ei, t, i, s, d);
    int pos = atomicAdd(&cursor[t * N + d], 1);
    csr_src[(size_t)t * EN + pos] = s;
}

// GAT softmax + aggregation + fused LN1, one block per (dst,t), atomic-free.
// Writes normalized nrm rows; raw (pre-LN) last-t row goes to xlast_g.
__global__ __launch_bounds__(128) void k_aggc(
        const int* __restrict__ offs, const int* __restrict__ csr_src,
        const float* __restrict__ a_s, const float* __restrict__ a_d,
        const float* __restrict__ xh, const float* __restrict__ b_gat,
        const float* __restrict__ g1, const float* __restrict__ be1,
        float* __restrict__ nrm, float* __restrict__ xlast_g) {
    int b = blockIdx.x;
    int t = b & 7;            // T == 8
    int dst = b >> 3;
    int tid = threadIdx.x;

    int o0 = offs[t * (N + 1) + dst];
    int o1 = offs[t * (N + 1) + dst + 1];
    int deg = o1 - o0;
    const int* esrc = csr_src + (size_t)t * EN + o0;
    const float* as_b = a_s + (size_t)t * N * H;
    const float* ad_b = a_d + (size_t)t * N * H;
    const float* xh_b = xh + (size_t)t * N * HID;

    __shared__ float lm[H][16], ls[H][16];
    __shared__ float fm[H], finv[H];
    __shared__ float lal[16][H];
    __shared__ int   lsrc[16];
    __shared__ float red[128];

    {
        int ha = tid & 7, l = tid >> 3;
        float ad_h = ad_b[dst * H + ha];
        float m = -1e30f, ssum = 0.0f;
        for (int i = l; i < deg; i += 16) {
            int src = esrc[i];
            float e = leaky(as_b[src * H + ha] + ad_h);
            if (e > m) { ssum = ssum * expf(m - e) + 1.0f; m = e; }
            else       { ssum += expf(e - m); }
        }
        lm[ha][l] = m;
        ls[ha][l] = ssum;
    }
    __syncthreads();
    if (tid < H) {
        float mm = -1e30f;
        for (int l = 0; l < 16; ++l) mm = fmaxf(mm, lm[tid][l]);
        float ss = 0.0f;
        for (int l = 0; l < 16; ++l) ss += ls[tid][l] * expf(lm[tid][l] - mm);
        fm[tid] = mm;
        finv[tid] = 1.0f / (ss + 1e-16f);
    }
    __syncthreads();

    int h = tid >> 4;
    int eh_e = tid >> 3, eh_h = tid & 7;
    float adh_e = ad_b[dst * H + eh_h];
    float fm_e = fm[eh_h], finv_e = finv[eh_h];
    float acc = 0.0f;

    int full = deg & ~15;     // full 16-edge tiles
    int base = 0;
    for (; base < full; base += 16) {
        int src = esrc[base + eh_e];
        if (eh_h == 0) lsrc[eh_e] = src;
        float e = leaky(as_b[src * H + eh_h] + adh_e);
        lal[eh_e][eh_h] = expf(e - fm_e) * finv_e;
        __syncthreads();
        #pragma unroll
        for (int j = 0; j < 16; j += 4) {
            float l0 = lal[j + 0][h], l1 = lal[j + 1][h];
            float l2 = lal[j + 2][h], l3 = lal[j + 3][h];
            int s0 = lsrc[j + 0], s1 = lsrc[j + 1];
            int s2 = lsrc[j + 2], s3 = lsrc[j + 3];
            float v0 = xh_b[(size_t)s0 * HID + tid];
            float v1 = xh_b[(size_t)s1 * HID + tid];
            float v2 = xh_b[(size_t)s2 * HID + tid];
            float v3 = xh_b[(size_t)s3 * HID + tid];
            acc += l0 * v0 + l1 * v1 + l2 * v2 + l3 * v3;
        }
        __syncthreads();
    }
    if (base < deg) {
        int ej = base + eh_e;
        if (ej < deg) {
            int src = esrc[ej];
            if (eh_h == 0) lsrc[eh_e] = src;
            float e = leaky(as_b[src * H + eh_h] + adh_e);
            lal[eh_e][eh_h] = expf(e - fm_e) * finv_e;
        }
        __syncthreads();
        int lim = deg - base;
        for (int j = 0; j < lim; ++j)
            acc += lal[j][h] * xh_b[(size_t)lsrc[j] * HID + tid];
        __syncthreads();
    }

    // ---- fused LN1 over this (t,dst) row ----
    float v = acc + b_gat[tid];
    red[tid] = v;
    __syncthreads();
    if (tid < 64) {
        float s = red[tid] + red[tid + 64];
        #pragma unroll
        for (int m = 1; m < 64; m <<= 1) s += __shfl_xor(s, m);
        if (tid == 0) red[0] = s;
    }
    __syncthreads();
    float mu = red[0] * (1.0f / HID);
    __syncthreads();
    float dv = v - mu;
    red[tid] = dv * dv;
    __syncthreads();
    if (tid < 64) {
        float s = red[tid] + red[tid + 64];
        #pragma unroll
        for (int m = 1; m < 64; m <<= 1) s += __shfl_xor(s, m);
        if (tid == 0) red[0] = s;
    }
    __syncthreads();
    float rstd = rsqrtf(red[0] * (1.0f / HID) + 1e-5f);

    nrm[(size_t)(t * N + dst) * HID + tid] = dv * rstd * g1[tid] + be1[tid];
    if (t == T - 1) xlast_g[(size_t)dst * HID + tid] = v;
}

// tiled qkv GEMM over nrm rows: blocks [0,1250) compute k|v for all T*N rows
// (kv[row][0..127]=k, [128..255]=v); blocks [1250,1407) compute q for the
// last-t rows only (qlast[n][0..127]). Bias folded in. 32-row register tile:
// one float4 weight load feeds 16 FMAs, weights reused across 32 rows.
__global__ __launch_bounds__(256) void k_qkv(const float* __restrict__ nrm,
                                             const float* __restrict__ WTq,
                                             const float* __restrict__ b_qkv,
                                             float* __restrict__ kv,
                                             float* __restrict__ qlast) {
    __shared__ float at[MT][HID];
    const int NKV = (T * N) / MT;   // 1250
    int b = blockIdx.x;
    int tid = threadIdx.x;
    bool qp = (b >= NKV);
    int row0 = qp ? (b - NKV) * MT : b * MT;
    const float* src = qp ? nrm + (size_t)(T - 1) * N * HID : nrm;
    int rmax = qp ? N : T * N;

    for (int idx = tid; idx < MT * HID; idx += 256) {
        int r = idx >> 7, c = idx & 127;
        int row = row0 + r;
        at[r][c] = (row < rmax) ? src[(size_t)row * HID + c] : 0.0f;
    }
    __syncthreads();

    int cg = tid & 31, rg = tid >> 5;
    int c0 = cg * 4, r0 = rg * 4;

    int gb = qp ? 0 : 1, ge = qp ? 1 : 3;
    for (int g = gb; g < ge; ++g) {
        int co = g * 128 + c0;
        float4 b4 = *(const float4*)(b_qkv + co);
        float a00=b4.x,a01=b4.y,a02=b4.z,a03=b4.w;
        float a10=b4.x,a11=b4.y,a12=b4.z,a13=b4.w;
        float a20=b4.x,a21=b4.y,a22=b4.z,a23=b4.w;
        float a30=b4.x,a31=b4.y,a32=b4.z,a33=b4.w;
        for (int k = 0; k < HID; ++k) {
            float4 w = *(const float4*)(WTq + (size_t)k * 384 + co);
            float e0 = at[r0 + 0][k], e1 = at[r0 + 1][k];
            float e2 = at[r0 + 2][k], e3 = at[r0 + 3][k];
            a00 += e0*w.x; a01 += e0*w.y; a02 += e0*w.z; a03 += e0*w.w;
            a10 += e1*w.x; a11 += e1*w.y; a12 += e1*w.z; a13 += e1*w.w;
            a20 += e2*w.x; a21 += e2*w.y; a22 += e2*w.z; a23 += e2*w.w;
            a30 += e3*w.x; a31 += e3*w.y; a32 += e3*w.z; a33 += e3*w.w;
        }
        float4 v0; v0.x=a00; v0.y=a01; v0.z=a02; v0.w=a03;
        float4 v1; v1.x=a10; v1.y=a11; v1.z=a12; v1.w=a13;
        float4 v2; v2.x=a20; v2.y=a21; v2.z=a22; v2.w=a23;
        float4 v3; v3.x=a30; v3.y=a31; v3.z=a32; v3.w=a33;
        if (qp) {
            if (row0 + r0 + 0 < N) *(float4*)(qlast + (size_t)(row0+r0+0) * HID + c0) = v0;
            if (row0 + r0 + 1 < N) *(float4*)(qlast + (size_t)(row0+r0+1) * HID + c0) = v1;
            if (row0 + r0 + 2 < N) *(float4*)(qlast + (size_t)(row0+r0+2) * HID + c0) = v2;
            if (row0 + r0 + 3 < N) *(float4*)(qlast + (size_t)(row0+r0+3) * HID + c0) = v3;
        } else {
            int coff = (g - 1) * 128 + c0;
            *(float4*)(kv + (size_t)(row0+r0+0) * 256 + coff) = v0;
            *(float4*)(kv + (size_t)(row0+r0+1) * 256 + coff) = v1;
            *(float4*)(kv + (size_t)(row0+r0+2) * 256 + coff) = v2;
            *(float4*)(kv + (size_t)(row0+r0+3) * 256 + coff) = v3;
        }
    }
}

// per-node (slim): load k/v/q/xlast -> attention -> W_o -> LN2 -> out
__global__ __launch_bounds__(128) void k_node(
        const float* __restrict__ kv, const float* __restrict__ qlast,
        const float* __restrict__ xlast_g,
        const float* __restrict__ WoT, const float* __restrict__ b_o,
        const float* __restrict__ g2, const float* __restrict__ be2,
        const float* __restrict__ noise, float* __restrict__ out) {
    __shared__ float ql[HID];
    __shared__ float kl[H][T][D];
    __shared__ float vl[H][T][D];
    __shared__ float attn_l[H][T];
    __shared__ float ta[HID];
    __shared__ float red[128];

    int n = blockIdx.x;
    int tid = threadIdx.x;
    int hh = tid >> 4, dd = tid & 15;

    ql[tid] = qlast[(size_t)n * HID + tid];
    #pragma unroll
    for (int tt = 0; tt < T; ++tt) {
        const float* kvr = kv + (size_t)(tt * N + n) * 256;
        kl[hh][tt][dd] = kvr[tid];
        vl[hh][tt][dd] = kvr[128 + tid];
    }
    float xl = xlast_g[(size_t)n * HID + tid];
    __syncthreads();

    if (tid < H) {
        int hq = tid;
        float sc[T];
        float mx = -1e30f;
        #pragma unroll
        for (int tk = 0; tk < T; ++tk) {
            float a = 0.0f;
            #pragma unroll
            for (int d2 = 0; d2 < D; ++d2) a += ql[hq * D + d2] * kl[hq][tk][d2];
            a *= 0.25f;
            sc[tk] = a;
            mx = fmaxf(mx, a);
        }
        float ssum = 0.0f;
        #pragma unroll
        for (int tk = 0; tk < T; ++tk) { sc[tk] = expf(sc[tk] - mx); ssum += sc[tk]; }
        float inv = 1.0f / ssum;
        #pragma unroll
        for (int tk = 0; tk < T; ++tk) attn_l[hq][tk] = sc[tk] * inv;
    }
    __syncthreads();

    {
        float a = 0.0f;
        #pragma unroll
        for (int tk = 0; tk < T; ++tk) a += attn_l[hh][tk] * vl[hh][tk][dd];
        ta[tid] = a;
    }
    __syncthreads();

    // W_o + residual
    float o = b_o[tid];
    #pragma unroll 8
    for (int k = 0; k < HID; k += 4) {
        float4 t4 = *(const float4*)&ta[k];
        o += t4.x * WoT[(size_t)(k + 0) * 128 + tid]
           + t4.y * WoT[(size_t)(k + 1) * 128 + tid]
           + t4.z * WoT[(size_t)(k + 2) * 128 + tid]
           + t4.w * WoT[(size_t)(k + 3) * 128 + tid];
    }
    float x2 = xl + o;

    red[tid] = x2;
    __syncthreads();
    if (tid < 64) {
        float s = red[tid] + red[tid + 64];
        #pragma unroll
        for (int m = 1; m < 64; m <<= 1) s += __shfl_xor(s, m);
        if (tid == 0) red[0] = s;
    }
    __syncthreads();
    float mu2 = red[0] * (1.0f / HID);
    __syncthreads();
    float d2v = x2 - mu2;
    red[tid] = d2v * d2v;
    __syncthreads();
    if (tid < 64) {
        float s = red[tid] + red[tid + 64];
        #pragma unroll
        for (int m = 1; m < 64; m <<= 1) s += __shfl_xor(s, m);
        if (tid == 0) red[0] = s;
    }
    __syncthreads();
    float rstd2 = rsqrtf(red[0] * (1.0f / HID) + 1e-5f);

    float div = sinf(((float)n / (float)N) * 6.28f) * 0.1f;
    float emb = d2v * rstd2 * g2[tid] + be2[tid]
              + div + noise[(size_t)n * HID + tid] * 0.05f;
    out[(size_t)n * HID + tid] = emb;
}

// classifier: tiled h1 = emb@Wc1 + bc1 -> LN3 -> gelu -> logits
__global__ __launch_bounds__(256) void k_cls(const float* __restrict__ emb,
                                             const float* __restrict__ Wc1,
                                             const float* __restrict__ bc1,
                                             const float* __restrict__ gc,
                                             const float* __restrict__ bec,
                                             const float* __restrict__ Wc2,
                                             const float* __restrict__ bc2,
                                             float* __restrict__ out) {
    __shared__ float et[MT][HID];
    __shared__ float h1t[MT][HID + 1];
    int row0 = blockIdx.x * MT;
    int tid = threadIdx.x;

    for (int idx = tid; idx < MT * HID; idx += 256) {
        int r = idx >> 7, c = idx & 127;
        int row = row0 + r;
        et[r][c] = (row < N) ? emb[(size_t)row * HID + c] : 0.0f;
    }
    __syncthreads();

    {
        int cg = tid & 31, rg = tid >> 5;
        int c0 = cg * 4, r0 = rg * 4;
        float4 b4 = *(const float4*)(bc1 + c0);
        float a00=b4.x,a01=b4.y,a02=b4.z,a03=b4.w;
        float a10=b4.x,a11=b4.y,a12=b4.z,a13=b4.w;
        float a20=b4.x,a21=b4.y,a22=b4.z,a23=b4.w;
        float a30=b4.x,a31=b4.y,a32=b4.z,a33=b4.w;
        for (int k = 0; k < HID; ++k) {
            float4 w = *(const float4*)(Wc1 + (size_t)k * HID + c0);
            float e0 = et[r0 + 0][k], e1 = et[r0 + 1][k];
            float e2 = et[r0 + 2][k], e3 = et[r0 + 3][k];
            a00 += e0*w.x; a01 += e0*w.y; a02 += e0*w.z; a03 += e0*w.w;
            a10 += e1*w.x; a11 += e1*w.y; a12 += e1*w.z; a13 += e1*w.w;
            a20 += e2*w.x; a21 += e2*w.y; a22 += e2*w.z; a23 += e2*w.w;
            a30 += e3*w.x; a31 += e3*w.y; a32 += e3*w.z; a33 += e3*w.w;
        }
        h1t[r0+0][c0+0]=a00; h1t[r0+0][c0+1]=a01; h1t[r0+0][c0+2]=a02; h1t[r0+0][c0+3]=a03;
        h1t[r0+1][c0+0]=a10; h1t[r0+1][c0+1]=a11; h1t[r0+1][c0+2]=a12; h1t[r0+1][c0+3]=a13;
        h1t[r0+2][c0+0]=a20; h1t[r0+2][c0+1]=a21; h1t[r0+2][c0+2]=a22; h1t[r0+2][c0+3]=a23;
        h1t[r0+3][c0+0]=a30; h1t[r0+3][c0+1]=a31; h1t[r0+3][c0+2]=a32; h1t[r0+3][c0+3]=a33;
    }
    __syncthreads();

    // LN3 + gelu: 8 lanes per row (32 rows x 8 = 256 threads)
    {
        int r = tid >> 3, l = tid & 7;
        float p = 0.0f;
        #pragma unroll
        for (int k = 0; k < 16; ++k) p += h1t[r][l + 8 * k];
        #pragma unroll
        for (int m = 1; m < 8; m <<= 1) p += __shfl_xor(p, m);
        float mu = p * (1.0f / HID);
        float v = 0.0f;
        #pragma unroll
        for (int k = 0; k < 16; ++k) { float d = h1t[r][l + 8 * k] - mu; v += d * d; }
        #pragma unroll
        for (int m = 1; m < 8; m <<= 1) v += __shfl_xor(v, m);
        float rstd = rsqrtf(v * (1.0f / HID) + 1e-5f);
        #pragma unroll
        for (int k = 0; k < 16; ++k) {
            int c = l + 8 * k;
            float lnv = (h1t[r][c] - mu) * rstd * gc[c] + bec[c];
            h1t[r][c] = 0.5f * lnv * (1.0f + erff(lnv * 0.70710678118f));
        }
    }
    __syncthreads();

    // logits: 64 outputs (32 rows x 2)
    if (tid < MT * NC) {
        int r = tid >> 1, j = tid & 1;
        int row = row0 + r;
        if (row < N) {
            float acc = bc2[j];
            #pragma unroll 8
            for (int c = 0; c < HID; ++c) acc += h1t[r][c] * Wc2[c * NC + j];
            if (j == 1) acc += sinf((float)row * 0.5f) * 0.2f;
            out[(size_t)N * HID + (size_t)row * NC + j] = acc;
        }
    }
}

extern "C" void kernel_launch(void* const* d_in, const int* in_sizes, int n_in,
                              void* d_out, int out_size, void* d_ws, size_t ws_size,
                              hipStream_t stream) {
    const float* x      = (const float*)d_in[0];
    const int*   ei     = (const int*)d_in[1];
    const float* noise  = (const float*)d_in[2];
    const float* W_proj = (const float*)d_in[3];
    const float* b_proj = (const float*)d_in[4];
    const float* W_gat  = (const float*)d_in[5];
    const float* a_src  = (const float*)d_in[6];
    const float* a_dst  = (const float*)d_in[7];
    const float* b_gat  = (const float*)d_in[8];
    const float* g1     = (const float*)d_in[9];
    const float* be1    = (const float*)d_in[10];
    const float* W_qkv  = (const float*)d_in[11];
    const float* b_qkv  = (const float*)d_in[12];
    const float* W_o    = (const float*)d_in[13];
    const float* b_o    = (const float*)d_in[14];
    const float* g2     = (const float*)d_in[15];
    const float* be2    = (const float*)d_in[16];
    const float* Wc1    = (const float*)d_in[17];
    const float* bc1    = (const float*)d_in[18];
    const float* gc     = (const float*)d_in[19];
    const float* bec    = (const float*)d_in[20];
    const float* Wc2    = (const float*)d_in[21];
    const float* bc2    = (const float*)d_in[22];
    float* out = (float*)d_out;

    float* xh     = (float*)d_ws;                  //  5,120,000
    float* nrm    = xh + 5120000;                  //  5,120,000
    float* a_s    = nrm + 5120000;                 //    320,000
    float* a_d    = a_s + 320000;                  //    320,000
    int*   offs    = (int*)(a_d + 320000);         //     40,008
    int*   cursor  = offs + 40008;                 //     40,000
    int*   csr_src = cursor + 40000;               //  1,320,000
    float* WTq    = (float*)(csr_src + 1320000);   //     49,152
    float* WoT    = WTq + 49152;                   //     16,384
    float* kv     = WoT + 16384;                   // 10,240,000
    float* qlast  = kv + 10240000;                 //    640,000
    float* xlastg = qlast + 640000;                //    640,000

    k_tr<<<(384 * 128 + 128 * 128 + 255) / 256, 256, 0, stream>>>(W_qkv, W_o, WTq, WoT);

    k_pg<<<T * N / MT, 256, 0, stream>>>(x, W_proj, b_proj, W_gat, a_src, a_dst,
                                         xh, a_s, a_d, cursor);

    k_hist<<<(T * EN + 255) / 256, 256, 0, stream>>>(ei, cursor);
    k_scan<<<T, 256, 0, stream>>>(cursor, offs);
    k_scatter<<<(T * EN + 255) / 256, 256, 0, stream>>>(ei, cursor, csr_src);

    k_aggc<<<T * N, 128, 0, stream>>>(offs, csr_src, a_s, a_d, xh,
                                      b_gat, g1, be1, nrm, xlastg);

    k_qkv<<<(T * N) / MT + (N + MT - 1) / MT, 256, 0, stream>>>(nrm, WTq, b_qkv,
                                                                kv, qlast);

    k_node<<<N, 128, 0, stream>>>(kv, qlast, xlastg, WoT, b_o,
                                  g2, be2, noise, out);

    k_cls<<<(N + MT - 1) / MT, 256, 0, stream>>>(out, Wc1, bc1, gc, bec, Wc2, bc2, out);
}

// Round 4
// 429.639 us; speedup vs baseline: 1.0798x; 1.0798x over previous
//
#include <hip/hip_runtime.h>
#include <math.h>

#define T 8
#define N 5000
#define E 160000
#define EN (E + N)
#define IN_DIM 64
#define HID 128
#define H 8
#define D 16
#define NC 2
#define MT 32            // rows per tiled-GEMM block

__device__ __forceinline__ float leaky(float e) { return (e >= 0.0f) ? e : 0.2f * e; }

// fused h=relu(x@Wp+bp); xh=h@Wg; a_s/a_d coef epilogue. Also zeroes cursor.
__global__ __launch_bounds__(256) void k_pg(const float* __restrict__ x,
                                            const float* __restrict__ Wp,
                                            const float* __restrict__ bp,
                                            const float* __restrict__ Wg,
                                            const float* __restrict__ asrc,
                                            const float* __restrict__ adst,
                                            float* __restrict__ xh,
                                            float* __restrict__ a_s,
                                            float* __restrict__ a_d,
                                            int* __restrict__ cursor) {
    __shared__ float xt[MT][IN_DIM];
    __shared__ float ht[MT][HID + 1];
    int row0 = blockIdx.x * MT;
    int tid = threadIdx.x;

    {   // fold the cursor memset into this kernel (runs before k_hist)
        int gi = blockIdx.x * 256 + tid;
        if (gi < T * N) cursor[gi] = 0;
    }

    for (int idx = tid; idx < MT * IN_DIM; idx += 256) {
        int r = idx >> 6, k = idx & 63;
        xt[r][k] = x[(size_t)(row0 + r) * IN_DIM + k];
    }
    __syncthreads();

    int cg = tid & 31;
    int rg = tid >> 5;
    int c0 = cg * 4, r0 = rg * 4;

    {
        float4 b4 = *(const float4*)(bp + c0);
        float a00=b4.x,a01=b4.y,a02=b4.z,a03=b4.w;
        float a10=b4.x,a11=b4.y,a12=b4.z,a13=b4.w;
        float a20=b4.x,a21=b4.y,a22=b4.z,a23=b4.w;
        float a30=b4.x,a31=b4.y,a32=b4.z,a33=b4.w;
        for (int k = 0; k < IN_DIM; ++k) {
            float4 w = *(const float4*)(Wp + (size_t)k * HID + c0);
            float x0 = xt[r0 + 0][k], x1 = xt[r0 + 1][k];
            float x2 = xt[r0 + 2][k], x3 = xt[r0 + 3][k];
            a00 += x0*w.x; a01 += x0*w.y; a02 += x0*w.z; a03 += x0*w.w;
            a10 += x1*w.x; a11 += x1*w.y; a12 += x1*w.z; a13 += x1*w.w;
            a20 += x2*w.x; a21 += x2*w.y; a22 += x2*w.z; a23 += x2*w.w;
            a30 += x3*w.x; a31 += x3*w.y; a32 += x3*w.z; a33 += x3*w.w;
        }
        ht[r0+0][c0+0]=fmaxf(a00,0.f); ht[r0+0][c0+1]=fmaxf(a01,0.f);
        ht[r0+0][c0+2]=fmaxf(a02,0.f); ht[r0+0][c0+3]=fmaxf(a03,0.f);
        ht[r0+1][c0+0]=fmaxf(a10,0.f); ht[r0+1][c0+1]=fmaxf(a11,0.f);
        ht[r0+1][c0+2]=fmaxf(a12,0.f); ht[r0+1][c0+3]=fmaxf(a13,0.f);
        ht[r0+2][c0+0]=fmaxf(a20,0.f); ht[r0+2][c0+1]=fmaxf(a21,0.f);
        ht[r0+2][c0+2]=fmaxf(a22,0.f); ht[r0+2][c0+3]=fmaxf(a23,0.f);
        ht[r0+3][c0+0]=fmaxf(a30,0.f); ht[r0+3][c0+1]=fmaxf(a31,0.f);
        ht[r0+3][c0+2]=fmaxf(a32,0.f); ht[r0+3][c0+3]=fmaxf(a33,0.f);
    }
    __syncthreads();

    float a00=0,a01=0,a02=0,a03=0, a10=0,a11=0,a12=0,a13=0;
    float a20=0,a21=0,a22=0,a23=0, a30=0,a31=0,a32=0,a33=0;
    for (int k = 0; k < HID; ++k) {
        float4 w = *(const float4*)(Wg + (size_t)k * HID + c0);
        float h0 = ht[r0 + 0][k], h1 = ht[r0 + 1][k];
        float h2 = ht[r0 + 2][k], h3 = ht[r0 + 3][k];
        a00 += h0*w.x; a01 += h0*w.y; a02 += h0*w.z; a03 += h0*w.w;
        a10 += h1*w.x; a11 += h1*w.y; a12 += h1*w.z; a13 += h1*w.w;
        a20 += h2*w.x; a21 += h2*w.y; a22 += h2*w.z; a23 += h2*w.w;
        a30 += h3*w.x; a31 += h3*w.y; a32 += h3*w.z; a33 += h3*w.w;
    }
    {
        float4 v;
        v.x=a00; v.y=a01; v.z=a02; v.w=a03;
        *(float4*)(xh + (size_t)(row0 + r0 + 0) * HID + c0) = v;
        v.x=a10; v.y=a11; v.z=a12; v.w=a13;
        *(float4*)(xh + (size_t)(row0 + r0 + 1) * HID + c0) = v;
        v.x=a20; v.y=a21; v.z=a22; v.w=a23;
        *(float4*)(xh + (size_t)(row0 + r0 + 2) * HID + c0) = v;
        v.x=a30; v.y=a31; v.z=a32; v.w=a33;
        *(float4*)(xh + (size_t)(row0 + r0 + 3) * HID + c0) = v;
    }
    __syncthreads();
    ht[r0+0][c0+0]=a00; ht[r0+0][c0+1]=a01; ht[r0+0][c0+2]=a02; ht[r0+0][c0+3]=a03;
    ht[r0+1][c0+0]=a10; ht[r0+1][c0+1]=a11; ht[r0+1][c0+2]=a12; ht[r0+1][c0+3]=a13;
    ht[r0+2][c0+0]=a20; ht[r0+2][c0+1]=a21; ht[r0+2][c0+2]=a22; ht[r0+2][c0+3]=a23;
    ht[r0+3][c0+0]=a30; ht[r0+3][c0+1]=a31; ht[r0+3][c0+2]=a32; ht[r0+3][c0+3]=a33;
    __syncthreads();

    {
        int r = tid >> 3, hh = tid & 7;
        float s1 = 0.0f, s2 = 0.0f;
        #pragma unroll
        for (int d = 0; d < D; ++d) {
            float v = ht[r][hh * D + d];
            s1 += v * asrc[hh * D + d];
            s2 += v * adst[hh * D + d];
        }
        a_s[(size_t)(row0 + r) * H + hh] = s1;
        a_d[(size_t)(row0 + r) * H + hh] = s2;
    }
}

// transpose W_qkv (384x128 -> 128x384) and W_o (128x128 -> 128x128)
__global__ void k_tr(const float* __restrict__ W_qkv, const float* __restrict__ W_o,
                     float* __restrict__ WTq, float* __restrict__ WoT) {
    int idx = blockIdx.x * 256 + threadIdx.x;
    if (idx < 384 * 128) {
        int j = idx >> 7, c = idx & 127;
        WTq[c * 384 + j] = W_qkv[idx];
    } else if (idx < 384 * 128 + 128 * 128) {
        int r = idx - 384 * 128;
        int j = r >> 7, k = r & 127;
        WoT[k * 128 + j] = W_o[r];
    }
}

__device__ __forceinline__ void esd_g(const int* __restrict__ ei, int t, int i,
                                      int& s, int& d) {
    if (i < E) {
        s = ei[(size_t)(2 * t) * E + i];
        d = ei[(size_t)(2 * t + 1) * E + i];
    } else {
        s = d = i - E;
    }
}

__global__ void k_hist(const int* __restrict__ ei, int* __restrict__ cursor) {
    int idx = blockIdx.x * 256 + threadIdx.x;
    if (idx >= T * EN) return;
    int t = idx / EN;
    int i = idx - t * EN;
    int s, d;
    esd_g(ei, t, i, s, d);
    atomicAdd(&cursor[t * N + d], 1);
}

__global__ void k_scan(int* __restrict__ cursor, int* __restrict__ offs) {
    __shared__ int part[256];
    int t = blockIdx.x;
    int tid = threadIdx.x;
    const int CH = 20;
    int begin = tid * CH;
    int sum = 0;
    for (int k = 0; k < CH; ++k) {
        int i = begin + k;
        if (i < N) sum += cursor[t * N + i];
    }
    part[tid] = sum;
    __syncthreads();
    if (tid == 0) {
        int run = 0;
        for (int i = 0; i < 256; ++i) { int v = part[i]; part[i] = run; run += v; }
        offs[t * (N + 1) + N] = run;
    }
    __syncthreads();
    int run = part[tid];
    for (int k = 0; k < CH; ++k) {
        int i = begin + k;
        if (i < N) {
            int cnt = cursor[t * N + i];
            offs[t * (N + 1) + i] = run;
            cursor[t * N + i] = run;
            run += cnt;
        }
    }
}

__global__ void k_scatter(const int* __restrict__ ei, int* __restrict__ cursor,
                          int* __restrict__ csr_src) {
    int idx = blockIdx.x * 256 + threadIdx.x;
    if (idx >= T * EN) return;
    int t = idx / EN;
    int i = idx - t * EN;
    int s, d;
    esd_g(ei, t, i, s, d);
    int pos = atomicAdd(&cursor[t * N + d], 1);
    csr_src[(size_t)t * EN + pos] = s;
}

// GAT aggregation + fused LN1, one block per (dst,t), atomic-free.
// Single-pass softmax: out = (sum w*xh)/(sum w), w = exp(leaky(e)) -- no
// max-subtraction pass (e is O(5), exp cannot overflow fp32).
// Gather loop: 4 edge-lanes x 32 col-groups, float4 loads (4 loads/tile/thread).
__global__ __launch_bounds__(128) void k_aggc(
        const int* __restrict__ offs, const int* __restrict__ csr_src,
        const float* __restrict__ a_s, const float* __restrict__ a_d,
        const float* __restrict__ xh, const float* __restrict__ b_gat,
        const float* __restrict__ g1, const float* __restrict__ be1,
        float* __restrict__ nrm, float* __restrict__ xlast_g) {
    int b = blockIdx.x;
    int t = b & 7;            // T == 8
    int dst = b >> 3;
    int tid = threadIdx.x;

    int o0 = offs[t * (N + 1) + dst];
    int o1 = offs[t * (N + 1) + dst + 1];
    int deg = o1 - o0;
    const int* esrc = csr_src + (size_t)t * EN + o0;
    const float* as_b = a_s + (size_t)t * N * H;
    const float* ad_b = a_d + (size_t)t * N * H;
    const float* xh_b = xh + (size_t)t * N * HID;

    __shared__ float lal[16][H];     // per-tile weights
    __shared__ int   lsrc[16];
    __shared__ float ws_s[2][H];     // per-wave wsum partials
    __shared__ float pacc[2][HID];   // per-wave acc partials
    __shared__ float red[128];

    int eh_e = tid >> 3, eh_h = tid & 7;   // lal-compute mapping
    int el = tid >> 5, cg = tid & 31;      // gather mapping
    int hg = cg >> 2;
    float adh_e = ad_b[dst * H + eh_h];

    float4 acc = {0.0f, 0.0f, 0.0f, 0.0f};
    float wpart = 0.0f;

    int ntile = (deg + 15) >> 4;
    for (int tt = 0; tt < ntile; ++tt) {
        int ej = (tt << 4) + eh_e;
        float w = 0.0f;
        int src = 0;
        if (ej < deg) {
            src = esrc[ej];
            w = expf(leaky(as_b[src * H + eh_h] + adh_e));
        }
        if (eh_h == 0) lsrc[eh_e] = src;
        lal[eh_e][eh_h] = w;
        wpart += w;
        __syncthreads();
        #pragma unroll
        for (int jj = 0; jj < 4; ++jj) {
            int j = (jj << 2) + el;
            int s = lsrc[j];
            float l = lal[j][hg];
            float4 v = *(const float4*)(xh_b + (size_t)s * HID + (cg << 2));
            acc.x += l * v.x; acc.y += l * v.y;
            acc.z += l * v.z; acc.w += l * v.w;
        }
        __syncthreads();
    }

    // reduce wsum over edge-slots (eh_e = lane bits 3..5 within wave + wave)
    {
        float w = wpart;
        w += __shfl_xor(w, 8);
        w += __shfl_xor(w, 16);
        w += __shfl_xor(w, 32);
        if ((tid & 63) < 8) ws_s[tid >> 6][eh_h] = w;
    }
    // reduce acc over edge-lanes (el bit 5 within wave + wave)
    acc.x += __shfl_xor(acc.x, 32);
    acc.y += __shfl_xor(acc.y, 32);
    acc.z += __shfl_xor(acc.z, 32);
    acc.w += __shfl_xor(acc.w, 32);
    if (!(tid & 32)) *(float4*)&pacc[tid >> 6][(tid & 31) << 2] = acc;
    __syncthreads();

    int hh = tid >> 4;
    float wsum = ws_s[0][hh] + ws_s[1][hh];
    float val = (pacc[0][tid] + pacc[1][tid]) / (wsum + 1e-16f);

    // ---- fused LN1 over this (t,dst) row ----
    float v = val + b_gat[tid];
    red[tid] = v;
    __syncthreads();
    if (tid < 64) {
        float s = red[tid] + red[tid + 64];
        #pragma unroll
        for (int m = 1; m < 64; m <<= 1) s += __shfl_xor(s, m);
        if (tid == 0) red[0] = s;
    }
    __syncthreads();
    float mu = red[0] * (1.0f / HID);
    __syncthreads();
    float dv = v - mu;
    red[tid] = dv * dv;
    __syncthreads();
    if (tid < 64) {
        float s = red[tid] + red[tid + 64];
        #pragma unroll
        for (int m = 1; m < 64; m <<= 1) s += __shfl_xor(s, m);
        if (tid == 0) red[0] = s;
    }
    __syncthreads();
    float rstd = rsqrtf(red[0] * (1.0f / HID) + 1e-5f);

    nrm[(size_t)(t * N + dst) * HID + tid] = dv * rstd * g1[tid] + be1[tid];
    if (t == T - 1) xlast_g[(size_t)dst * HID + tid] = v;
}

// tiled qkv GEMM over nrm rows: blocks [0,1250) compute k|v for all T*N rows
// (kv[row][0..127]=k, [128..255]=v); blocks [1250,1407) compute q for the
// last-t rows only (qlast[n][0..127]). Bias folded in. 32-row register tile:
// one float4 weight load feeds 16 FMAs, weights reused across 32 rows.
__global__ __launch_bounds__(256) void k_qkv(const float* __restrict__ nrm,
                                             const float* __restrict__ WTq,
                                             const float* __restrict__ b_qkv,
                                             float* __restrict__ kv,
                                             float* __restrict__ qlast) {
    __shared__ float at[MT][HID];
    const int NKV = (T * N) / MT;   // 1250
    int b = blockIdx.x;
    int tid = threadIdx.x;
    bool qp = (b >= NKV);
    int row0 = qp ? (b - NKV) * MT : b * MT;
    const float* src = qp ? nrm + (size_t)(T - 1) * N * HID : nrm;
    int rmax = qp ? N : T * N;

    for (int idx = tid; idx < MT * HID; idx += 256) {
        int r = idx >> 7, c = idx & 127;
        int row = row0 + r;
        at[r][c] = (row < rmax) ? src[(size_t)row * HID + c] : 0.0f;
    }
    __syncthreads();

    int cg = tid & 31, rg = tid >> 5;
    int c0 = cg * 4, r0 = rg * 4;

    int gb = qp ? 0 : 1, ge = qp ? 1 : 3;
    for (int g = gb; g < ge; ++g) {
        int co = g * 128 + c0;
        float4 b4 = *(const float4*)(b_qkv + co);
        float a00=b4.x,a01=b4.y,a02=b4.z,a03=b4.w;
        float a10=b4.x,a11=b4.y,a12=b4.z,a13=b4.w;
        float a20=b4.x,a21=b4.y,a22=b4.z,a23=b4.w;
        float a30=b4.x,a31=b4.y,a32=b4.z,a33=b4.w;
        for (int k = 0; k < HID; ++k) {
            float4 w = *(const float4*)(WTq + (size_t)k * 384 + co);
            float e0 = at[r0 + 0][k], e1 = at[r0 + 1][k];
            float e2 = at[r0 + 2][k], e3 = at[r0 + 3][k];
            a00 += e0*w.x; a01 += e0*w.y; a02 += e0*w.z; a03 += e0*w.w;
            a10 += e1*w.x; a11 += e1*w.y; a12 += e1*w.z; a13 += e1*w.w;
            a20 += e2*w.x; a21 += e2*w.y; a22 += e2*w.z; a23 += e2*w.w;
            a30 += e3*w.x; a31 += e3*w.y; a32 += e3*w.z; a33 += e3*w.w;
        }
        float4 v0; v0.x=a00; v0.y=a01; v0.z=a02; v0.w=a03;
        float4 v1; v1.x=a10; v1.y=a11; v1.z=a12; v1.w=a13;
        float4 v2; v2.x=a20; v2.y=a21; v2.z=a22; v2.w=a23;
        float4 v3; v3.x=a30; v3.y=a31; v3.z=a32; v3.w=a33;
        if (qp) {
            if (row0 + r0 + 0 < N) *(float4*)(qlast + (size_t)(row0+r0+0) * HID + c0) = v0;
            if (row0 + r0 + 1 < N) *(float4*)(qlast + (size_t)(row0+r0+1) * HID + c0) = v1;
            if (row0 + r0 + 2 < N) *(float4*)(qlast + (size_t)(row0+r0+2) * HID + c0) = v2;
            if (row0 + r0 + 3 < N) *(float4*)(qlast + (size_t)(row0+r0+3) * HID + c0) = v3;
        } else {
            int coff = (g - 1) * 128 + c0;
            *(float4*)(kv + (size_t)(row0+r0+0) * 256 + coff) = v0;
            *(float4*)(kv + (size_t)(row0+r0+1) * 256 + coff) = v1;
            *(float4*)(kv + (size_t)(row0+r0+2) * 256 + coff) = v2;
            *(float4*)(kv + (size_t)(row0+r0+3) * 256 + coff) = v3;
        }
    }
}

// per-node (slim): load k/v/q/xlast -> attention -> W_o -> LN2 -> out
__global__ __launch_bounds__(128) void k_node(
        const float* __restrict__ kv, const float* __restrict__ qlast,
        const float* __restrict__ xlast_g,
        const float* __restrict__ WoT, const float* __restrict__ b_o,
        const float* __restrict__ g2, const float* __restrict__ be2,
        const float* __restrict__ noise, float* __restrict__ out) {
    __shared__ float ql[HID];
    __shared__ float kl[H][T][D];
    __shared__ float vl[H][T][D];
    __shared__ float attn_l[H][T];
    __shared__ float ta[HID];
    __shared__ float red[128];

    int n = blockIdx.x;
    int tid = threadIdx.x;
    int hh = tid >> 4, dd = tid & 15;

    ql[tid] = qlast[(size_t)n * HID + tid];
    #pragma unroll
    for (int tt = 0; tt < T; ++tt) {
        const float* kvr = kv + (size_t)(tt * N + n) * 256;
        kl[hh][tt][dd] = kvr[tid];
        vl[hh][tt][dd] = kvr[128 + tid];
    }
    float xl = xlast_g[(size_t)n * HID + tid];
    __syncthreads();

    if (tid < H) {
        int hq = tid;
        float sc[T];
        float mx = -1e30f;
        #pragma unroll
        for (int tk = 0; tk < T; ++tk) {
            float a = 0.0f;
            #pragma unroll
            for (int d2 = 0; d2 < D; ++d2) a += ql[hq * D + d2] * kl[hq][tk][d2];
            a *= 0.25f;
            sc[tk] = a;
            mx = fmaxf(mx, a);
        }
        float ssum = 0.0f;
        #pragma unroll
        for (int tk = 0; tk < T; ++tk) { sc[tk] = expf(sc[tk] - mx); ssum += sc[tk]; }
        float inv = 1.0f / ssum;
        #pragma unroll
        for (int tk = 0; tk < T; ++tk) attn_l[hq][tk] = sc[tk] * inv;
    }
    __syncthreads();

    {
        float a = 0.0f;
        #pragma unroll
        for (int tk = 0; tk < T; ++tk) a += attn_l[hh][tk] * vl[hh][tk][dd];
        ta[tid] = a;
    }
    __syncthreads();

    // W_o + residual
    float o = b_o[tid];
    #pragma unroll 8
    for (int k = 0; k < HID; k += 4) {
        float4 t4 = *(const float4*)&ta[k];
        o += t4.x * WoT[(size_t)(k + 0) * 128 + tid]
           + t4.y * WoT[(size_t)(k + 1) * 128 + tid]
           + t4.z * WoT[(size_t)(k + 2) * 128 + tid]
           + t4.w * WoT[(size_t)(k + 3) * 128 + tid];
    }
    float x2 = xl + o;

    red[tid] = x2;
    __syncthreads();
    if (tid < 64) {
        float s = red[tid] + red[tid + 64];
        #pragma unroll
        for (int m = 1; m < 64; m <<= 1) s += __shfl_xor(s, m);
        if (tid == 0) red[0] = s;
    }
    __syncthreads();
    float mu2 = red[0] * (1.0f / HID);
    __syncthreads();
    float d2v = x2 - mu2;
    red[tid] = d2v * d2v;
    __syncthreads();
    if (tid < 64) {
        float s = red[tid] + red[tid + 64];
        #pragma unroll
        for (int m = 1; m < 64; m <<= 1) s += __shfl_xor(s, m);
        if (tid == 0) red[0] = s;
    }
    __syncthreads();
    float rstd2 = rsqrtf(red[0] * (1.0f / HID) + 1e-5f);

    float div = sinf(((float)n / (float)N) * 6.28f) * 0.1f;
    float emb = d2v * rstd2 * g2[tid] + be2[tid]
              + div + noise[(size_t)n * HID + tid] * 0.05f;
    out[(size_t)n * HID + tid] = emb;
}

// classifier: tiled h1 = emb@Wc1 + bc1 -> LN3 -> gelu -> logits
__global__ __launch_bounds__(256) void k_cls(const float* __restrict__ emb,
                                             const float* __restrict__ Wc1,
                                             const float* __restrict__ bc1,
                                             const float* __restrict__ gc,
                                             const float* __restrict__ bec,
                                             const float* __restrict__ Wc2,
                                             const float* __restrict__ bc2,
                                             float* __restrict__ out) {
    __shared__ float et[MT][HID];
    __shared__ float h1t[MT][HID + 1];
    int row0 = blockIdx.x * MT;
    int tid = threadIdx.x;

    for (int idx = tid; idx < MT * HID; idx += 256) {
        int r = idx >> 7, c = idx & 127;
        int row = row0 + r;
        et[r][c] = (row < N) ? emb[(size_t)row * HID + c] : 0.0f;
    }
    __syncthreads();

    {
        int cg = tid & 31, rg = tid >> 5;
        int c0 = cg * 4, r0 = rg * 4;
        float4 b4 = *(const float4*)(bc1 + c0);
        float a00=b4.x,a01=b4.y,a02=b4.z,a03=b4.w;
        float a10=b4.x,a11=b4.y,a12=b4.z,a13=b4.w;
        float a20=b4.x,a21=b4.y,a22=b4.z,a23=b4.w;
        float a30=b4.x,a31=b4.y,a32=b4.z,a33=b4.w;
        for (int k = 0; k < HID; ++k) {
            float4 w = *(const float4*)(Wc1 + (size_t)k * HID + c0);
            float e0 = et[r0 + 0][k], e1 = et[r0 + 1][k];
            float e2 = et[r0 + 2][k], e3 = et[r0 + 3][k];
            a00 += e0*w.x; a01 += e0*w.y; a02 += e0*w.z; a03 += e0*w.w;
            a10 += e1*w.x; a11 += e1*w.y; a12 += e1*w.z; a13 += e1*w.w;
            a20 += e2*w.x; a21 += e2*w.y; a22 += e2*w.z; a23 += e2*w.w;
            a30 += e3*w.x; a31 += e3*w.y; a32 += e3*w.z; a33 += e3*w.w;
        }
        h1t[r0+0][c0+0]=a00; h1t[r0+0][c0+1]=a01; h1t[r0+0][c0+2]=a02; h1t[r0+0][c0+3]=a03;
        h1t[r0+1][c0+0]=a10; h1t[r0+1][c0+1]=a11; h1t[r0+1][c0+2]=a12; h1t[r0+1][c0+3]=a13;
        h1t[r0+2][c0+0]=a20; h1t[r0+2][c0+1]=a21; h1t[r0+2][c0+2]=a22; h1t[r0+2][c0+3]=a23;
        h1t[r0+3][c0+0]=a30; h1t[r0+3][c0+1]=a31; h1t[r0+3][c0+2]=a32; h1t[r0+3][c0+3]=a33;
    }
    __syncthreads();

    // LN3 + gelu: 8 lanes per row (32 rows x 8 = 256 threads)
    {
        int r = tid >> 3, l = tid & 7;
        float p = 0.0f;
        #pragma unroll
        for (int k = 0; k < 16; ++k) p += h1t[r][l + 8 * k];
        #pragma unroll
        for (int m = 1; m < 8; m <<= 1) p += __shfl_xor(p, m);
        float mu = p * (1.0f / HID);
        float v = 0.0f;
        #pragma unroll
        for (int k = 0; k < 16; ++k) { float d = h1t[r][l + 8 * k] - mu; v += d * d; }
        #pragma unroll
        for (int m = 1; m < 8; m <<= 1) v += __shfl_xor(v, m);
        float rstd = rsqrtf(v * (1.0f / HID) + 1e-5f);
        #pragma unroll
        for (int k = 0; k < 16; ++k) {
            int c = l + 8 * k;
            float lnv = (h1t[r][c] - mu) * rstd * gc[c] + bec[c];
            h1t[r][c] = 0.5f * lnv * (1.0f + erff(lnv * 0.70710678118f));
        }
    }
    __syncthreads();

    // logits: 64 outputs (32 rows x 2)
    if (tid < MT * NC) {
        int r = tid >> 1, j = tid & 1;
        int row = row0 + r;
        if (row < N) {
            float acc = bc2[j];
            #pragma unroll 8
            for (int c = 0; c < HID; ++c) acc += h1t[r][c] * Wc2[c * NC + j];
            if (j == 1) acc += sinf((float)row * 0.5f) * 0.2f;
            out[(size_t)N * HID + (size_t)row * NC + j] = acc;
        }
    }
}

extern "C" void kernel_launch(void* const* d_in, const int* in_sizes, int n_in,
                              void* d_out, int out_size, void* d_ws, size_t ws_size,
                              hipStream_t stream) {
    const float* x      = (const float*)d_in[0];
    const int*   ei     = (const int*)d_in[1];
    const float* noise  = (const float*)d_in[2];
    const float* W_proj = (const float*)d_in[3];
    const float* b_proj = (const float*)d_in[4];
    const float* W_gat  = (const float*)d_in[5];
    const float* a_src  = (const float*)d_in[6];
    const float* a_dst  = (const float*)d_in[7];
    const float* b_gat  = (const float*)d_in[8];
    const float* g1     = (const float*)d_in[9];
    const float* be1    = (const float*)d_in[10];
    const float* W_qkv  = (const float*)d_in[11];
    const float* b_qkv  = (const float*)d_in[12];
    const float* W_o    = (const float*)d_in[13];
    const float* b_o    = (const float*)d_in[14];
    const float* g2     = (const float*)d_in[15];
    const float* be2    = (const float*)d_in[16];
    const float* Wc1    = (const float*)d_in[17];
    const float* bc1    = (const float*)d_in[18];
    const float* gc     = (const float*)d_in[19];
    const float* bec    = (const float*)d_in[20];
    const float* Wc2    = (const float*)d_in[21];
    const float* bc2    = (const float*)d_in[22];
    float* out = (float*)d_out;

    float* xh     = (float*)d_ws;                  //  5,120,000
    float* nrm    = xh + 5120000;                  //  5,120,000
    float* a_s    = nrm + 5120000;                 //    320,000
    float* a_d    = a_s + 320000;                  //    320,000
    int*   offs    = (int*)(a_d + 320000);         //     40,008
    int*   cursor  = offs + 40008;                 //     40,000
    int*   csr_src = cursor + 40000;               //  1,320,000
    float* WTq    = (float*)(csr_src + 1320000);   //     49,152
    float* WoT    = WTq + 49152;                   //     16,384
    float* kv     = WoT + 16384;                   // 10,240,000
    float* qlast  = kv + 10240000;                 //    640,000
    float* xlastg = qlast + 640000;                //    640,000

    k_tr<<<(384 * 128 + 128 * 128 + 255) / 256, 256, 0, stream>>>(W_qkv, W_o, WTq, WoT);

    k_pg<<<T * N / MT, 256, 0, stream>>>(x, W_proj, b_proj, W_gat, a_src, a_dst,
                                         xh, a_s, a_d, cursor);

    k_hist<<<(T * EN + 255) / 256, 256, 0, stream>>>(ei, cursor);
    k_scan<<<T, 256, 0, stream>>>(cursor, offs);
    k_scatter<<<(T * EN + 255) / 256, 256, 0, stream>>>(ei, cursor, csr_src);

    k_aggc<<<T * N, 128, 0, stream>>>(offs, csr_src, a_s, a_d, xh,
                                      b_gat, g1, be1, nrm, xlastg);

    k_qkv<<<(T * N) / MT + (N + MT - 1) / MT, 256, 0, stream>>>(nrm, WTq, b_qkv,
                                                                kv, qlast);

    k_node<<<N, 128, 0, stream>>>(kv, qlast, xlastg, WoT, b_o,
                                  g2, be2, noise, out);

    k_cls<<<(N + MT - 1) / MT, 256, 0, stream>>>(out, Wc1, bc1, gc, bec, Wc2, bc2, out);
}

// Round 5
// 393.445 us; speedup vs baseline: 1.1792x; 1.0920x over previous
//
#include <hip/hip_runtime.h>
#include <math.h>

#define T 8
#define N 5000
#define E 160000
#define EN (E + N)
#define IN_DIM 64
#define HID 128
#define H 8
#define D 16
#define NC 2
#define MT 32            // rows per tiled-GEMM block

__device__ __forceinline__ float leaky(float e) { return (e >= 0.0f) ? e : 0.2f * e; }

// fused h=relu(x@Wp+bp); xh=h@Wg; a_s/a_d coef epilogue. Also zeroes cursor.
__global__ __launch_bounds__(256) void k_pg(const float* __restrict__ x,
                                            const float* __restrict__ Wp,
                                            const float* __restrict__ bp,
                                            const float* __restrict__ Wg,
                                            const float* __restrict__ asrc,
                                            const float* __restrict__ adst,
                                            float* __restrict__ xh,
                                            float* __restrict__ a_s,
                                            float* __restrict__ a_d,
                                            int* __restrict__ cursor) {
    __shared__ float xt[MT][IN_DIM];
    __shared__ float ht[MT][HID + 1];
    int row0 = blockIdx.x * MT;
    int tid = threadIdx.x;

    {   // fold the cursor memset into this kernel (runs before k_hist)
        int gi = blockIdx.x * 256 + tid;
        if (gi < T * N) cursor[gi] = 0;
    }

    for (int idx = tid; idx < MT * IN_DIM; idx += 256) {
        int r = idx >> 6, k = idx & 63;
        xt[r][k] = x[(size_t)(row0 + r) * IN_DIM + k];
    }
    __syncthreads();

    int cg = tid & 31;
    int rg = tid >> 5;
    int c0 = cg * 4, r0 = rg * 4;

    {
        float4 b4 = *(const float4*)(bp + c0);
        float a00=b4.x,a01=b4.y,a02=b4.z,a03=b4.w;
        float a10=b4.x,a11=b4.y,a12=b4.z,a13=b4.w;
        float a20=b4.x,a21=b4.y,a22=b4.z,a23=b4.w;
        float a30=b4.x,a31=b4.y,a32=b4.z,a33=b4.w;
        for (int k = 0; k < IN_DIM; ++k) {
            float4 w = *(const float4*)(Wp + (size_t)k * HID + c0);
            float x0 = xt[r0 + 0][k], x1 = xt[r0 + 1][k];
            float x2 = xt[r0 + 2][k], x3 = xt[r0 + 3][k];
            a00 += x0*w.x; a01 += x0*w.y; a02 += x0*w.z; a03 += x0*w.w;
            a10 += x1*w.x; a11 += x1*w.y; a12 += x1*w.z; a13 += x1*w.w;
            a20 += x2*w.x; a21 += x2*w.y; a22 += x2*w.z; a23 += x2*w.w;
            a30 += x3*w.x; a31 += x3*w.y; a32 += x3*w.z; a33 += x3*w.w;
        }
        ht[r0+0][c0+0]=fmaxf(a00,0.f); ht[r0+0][c0+1]=fmaxf(a01,0.f);
        ht[r0+0][c0+2]=fmaxf(a02,0.f); ht[r0+0][c0+3]=fmaxf(a03,0.f);
        ht[r0+1][c0+0]=fmaxf(a10,0.f); ht[r0+1][c0+1]=fmaxf(a11,0.f);
        ht[r0+1][c0+2]=fmaxf(a12,0.f); ht[r0+1][c0+3]=fmaxf(a13,0.f);
        ht[r0+2][c0+0]=fmaxf(a20,0.f); ht[r0+2][c0+1]=fmaxf(a21,0.f);
        ht[r0+2][c0+2]=fmaxf(a22,0.f); ht[r0+2][c0+3]=fmaxf(a23,0.f);
        ht[r0+3][c0+0]=fmaxf(a30,0.f); ht[r0+3][c0+1]=fmaxf(a31,0.f);
        ht[r0+3][c0+2]=fmaxf(a32,0.f); ht[r0+3][c0+3]=fmaxf(a33,0.f);
    }
    __syncthreads();

    float a00=0,a01=0,a02=0,a03=0, a10=0,a11=0,a12=0,a13=0;
    float a20=0,a21=0,a22=0,a23=0, a30=0,a31=0,a32=0,a33=0;
    for (int k = 0; k < HID; ++k) {
        float4 w = *(const float4*)(Wg + (size_t)k * HID + c0);
        float h0 = ht[r0 + 0][k], h1 = ht[r0 + 1][k];
        float h2 = ht[r0 + 2][k], h3 = ht[r0 + 3][k];
        a00 += h0*w.x; a01 += h0*w.y; a02 += h0*w.z; a03 += h0*w.w;
        a10 += h1*w.x; a11 += h1*w.y; a12 += h1*w.z; a13 += h1*w.w;
        a20 += h2*w.x; a21 += h2*w.y; a22 += h2*w.z; a23 += h2*w.w;
        a30 += h3*w.x; a31 += h3*w.y; a32 += h3*w.z; a33 += h3*w.w;
    }
    {
        float4 v;
        v.x=a00; v.y=a01; v.z=a02; v.w=a03;
        *(float4*)(xh + (size_t)(row0 + r0 + 0) * HID + c0) = v;
        v.x=a10; v.y=a11; v.z=a12; v.w=a13;
        *(float4*)(xh + (size_t)(row0 + r0 + 1) * HID + c0) = v;
        v.x=a20; v.y=a21; v.z=a22; v.w=a23;
        *(float4*)(xh + (size_t)(row0 + r0 + 2) * HID + c0) = v;
        v.x=a30; v.y=a31; v.z=a32; v.w=a33;
        *(float4*)(xh + (size_t)(row0 + r0 + 3) * HID + c0) = v;
    }
    __syncthreads();
    ht[r0+0][c0+0]=a00; ht[r0+0][c0+1]=a01; ht[r0+0][c0+2]=a02; ht[r0+0][c0+3]=a03;
    ht[r0+1][c0+0]=a10; ht[r0+1][c0+1]=a11; ht[r0+1][c0+2]=a12; ht[r0+1][c0+3]=a13;
    ht[r0+2][c0+0]=a20; ht[r0+2][c0+1]=a21; ht[r0+2][c0+2]=a22; ht[r0+2][c0+3]=a23;
    ht[r0+3][c0+0]=a30; ht[r0+3][c0+1]=a31; ht[r0+3][c0+2]=a32; ht[r0+3][c0+3]=a33;
    __syncthreads();

    {
        int r = tid >> 3, hh = tid & 7;
        float s1 = 0.0f, s2 = 0.0f;
        #pragma unroll
        for (int d = 0; d < D; ++d) {
            float v = ht[r][hh * D + d];
            s1 += v * asrc[hh * D + d];
            s2 += v * adst[hh * D + d];
        }
        a_s[(size_t)(row0 + r) * H + hh] = s1;
        a_d[(size_t)(row0 + r) * H + hh] = s2;
    }
}

// transpose W_qkv (384x128 -> 128x384) and W_o (128x128 -> 128x128)
__global__ void k_tr(const float* __restrict__ W_qkv, const float* __restrict__ W_o,
                     float* __restrict__ WTq, float* __restrict__ WoT) {
    int idx = blockIdx.x * 256 + threadIdx.x;
    if (idx < 384 * 128) {
        int j = idx >> 7, c = idx & 127;
        WTq[c * 384 + j] = W_qkv[idx];
    } else if (idx < 384 * 128 + 128 * 128) {
        int r = idx - 384 * 128;
        int j = r >> 7, k = r & 127;
        WoT[k * 128 + j] = W_o[r];
    }
}

// LDS-privatized degree histogram: T*8 blocks, each histograms ~EN/8 edges
// of one t into LDS, then flushes 5000 coalesced global atomics.
__global__ __launch_bounds__(256) void k_hist(const int* __restrict__ ei,
                                              int* __restrict__ cursor) {
    __shared__ int hist[N];          // 20 KB
    int t = blockIdx.x >> 3;
    int chunk = blockIdx.x & 7;
    int tid = threadIdx.x;

    for (int i = tid; i < N; i += 256) hist[i] = 0;
    __syncthreads();

    const int CS = (EN + 7) / 8;     // 20625
    int i0 = chunk * CS;
    int i1 = (i0 + CS < EN) ? i0 + CS : EN;
    const int* drow = ei + (size_t)(2 * t + 1) * E;
    for (int i = i0 + tid; i < i1; i += 256) {
        int d = (i < E) ? drow[i] : (i - E);
        atomicAdd(&hist[d], 1);
    }
    __syncthreads();

    int* cur = cursor + t * N;
    for (int i = tid; i < N; i += 256) {
        int c = hist[i];
        if (c) atomicAdd(&cur[i], c);
    }
}

__global__ void k_scan(int* __restrict__ cursor, int* __restrict__ offs) {
    __shared__ int part[256];
    int t = blockIdx.x;
    int tid = threadIdx.x;
    const int CH = 20;
    int begin = tid * CH;
    int sum = 0;
    for (int k = 0; k < CH; ++k) {
        int i = begin + k;
        if (i < N) sum += cursor[t * N + i];
    }
    part[tid] = sum;
    __syncthreads();
    if (tid == 0) {
        int run = 0;
        for (int i = 0; i < 256; ++i) { int v = part[i]; part[i] = run; run += v; }
        offs[t * (N + 1) + N] = run;
    }
    __syncthreads();
    int run = part[tid];
    for (int k = 0; k < CH; ++k) {
        int i = begin + k;
        if (i < N) {
            int cnt = cursor[t * N + i];
            offs[t * (N + 1) + i] = run;
            cursor[t * N + i] = run;
            run += cnt;
        }
    }
}

// scatter with 4-edge ILP per thread (strided within one t for coalescing):
// 4 independent atomic chains per thread hide atomic latency.
__global__ __launch_bounds__(256) void k_scatter(const int* __restrict__ ei,
                                                 int* __restrict__ cursor,
                                                 int* __restrict__ csr_src) {
    const int PT = EN / 4;           // 41250 threads per t
    int idx = blockIdx.x * 256 + threadIdx.x;
    int t = idx / PT;
    if (t >= T) return;
    int e0 = idx - t * PT;

    const int* srow = ei + (size_t)(2 * t) * E;
    const int* drow = srow + E;
    int s[4], d[4];
    #pragma unroll
    for (int j = 0; j < 4; ++j) {
        int i = e0 + j * PT;
        if (i < E) { s[j] = srow[i]; d[j] = drow[i]; }
        else       { s[j] = d[j] = i - E; }
    }
    int* cur = cursor + t * N;
    int p[4];
    #pragma unroll
    for (int j = 0; j < 4; ++j) p[j] = atomicAdd(&cur[d[j]], 1);
    int* csb = csr_src + (size_t)t * EN;
    #pragma unroll
    for (int j = 0; j < 4; ++j) csb[p[j]] = s[j];
}

// GAT aggregation + fused LN1, one block per (dst,t), atomic-free.
// Single-pass softmax: out = (sum w*xh)/(sum w), w = exp(leaky(e)) -- no
// max-subtraction pass (e is O(5), exp cannot overflow fp32).
// Gather loop: 4 edge-lanes x 32 col-groups, float4 loads (4 loads/tile/thread).
__global__ __launch_bounds__(128) void k_aggc(
        const int* __restrict__ offs, const int* __restrict__ csr_src,
        const float* __restrict__ a_s, const float* __restrict__ a_d,
        const float* __restrict__ xh, const float* __restrict__ b_gat,
        const float* __restrict__ g1, const float* __restrict__ be1,
        float* __restrict__ nrm, float* __restrict__ xlast_g) {
    int b = blockIdx.x;
    int t = b & 7;            // T == 8
    int dst = b >> 3;
    int tid = threadIdx.x;

    int o0 = offs[t * (N + 1) + dst];
    int o1 = offs[t * (N + 1) + dst + 1];
    int deg = o1 - o0;
    const int* esrc = csr_src + (size_t)t * EN + o0;
    const float* as_b = a_s + (size_t)t * N * H;
    const float* ad_b = a_d + (size_t)t * N * H;
    const float* xh_b = xh + (size_t)t * N * HID;

    __shared__ float lal[16][H];     // per-tile weights
    __shared__ int   lsrc[16];
    __shared__ float ws_s[2][H];     // per-wave wsum partials
    __shared__ float pacc[2][HID];   // per-wave acc partials
    __shared__ float red[128];

    int eh_e = tid >> 3, eh_h = tid & 7;   // lal-compute mapping
    int el = tid >> 5, cg = tid & 31;      // gather mapping
    int hg = cg >> 2;
    float adh_e = ad_b[dst * H + eh_h];

    float4 acc = {0.0f, 0.0f, 0.0f, 0.0f};
    float wpart = 0.0f;

    int ntile = (deg + 15) >> 4;
    for (int tt = 0; tt < ntile; ++tt) {
        int ej = (tt << 4) + eh_e;
        float w = 0.0f;
        int src = 0;
        if (ej < deg) {
            src = esrc[ej];
            w = expf(leaky(as_b[src * H + eh_h] + adh_e));
        }
        if (eh_h == 0) lsrc[eh_e] = src;
        lal[eh_e][eh_h] = w;
        wpart += w;
        __syncthreads();
        #pragma unroll
        for (int jj = 0; jj < 4; ++jj) {
            int j = (jj << 2) + el;
            int s = lsrc[j];
            float l = lal[j][hg];
            float4 v = *(const float4*)(xh_b + (size_t)s * HID + (cg << 2));
            acc.x += l * v.x; acc.y += l * v.y;
            acc.z += l * v.z; acc.w += l * v.w;
        }
        __syncthreads();
    }

    // reduce wsum over edge-slots (eh_e = lane bits 3..5 within wave + wave)
    {
        float w = wpart;
        w += __shfl_xor(w, 8);
        w += __shfl_xor(w, 16);
        w += __shfl_xor(w, 32);
        if ((tid & 63) < 8) ws_s[tid >> 6][eh_h] = w;
    }
    // reduce acc over edge-lanes (el bit 5 within wave + wave)
    acc.x += __shfl_xor(acc.x, 32);
    acc.y += __shfl_xor(acc.y, 32);
    acc.z += __shfl_xor(acc.z, 32);
    acc.w += __shfl_xor(acc.w, 32);
    if (!(tid & 32)) *(float4*)&pacc[tid >> 6][(tid & 31) << 2] = acc;
    __syncthreads();

    int hh = tid >> 4;
    float wsum = ws_s[0][hh] + ws_s[1][hh];
    float val = (pacc[0][tid] + pacc[1][tid]) / (wsum + 1e-16f);

    // ---- fused LN1 over this (t,dst) row ----
    float v = val + b_gat[tid];
    red[tid] = v;
    __syncthreads();
    if (tid < 64) {
        float s = red[tid] + red[tid + 64];
        #pragma unroll
        for (int m = 1; m < 64; m <<= 1) s += __shfl_xor(s, m);
        if (tid == 0) red[0] = s;
    }
    __syncthreads();
    float mu = red[0] * (1.0f / HID);
    __syncthreads();
    float dv = v - mu;
    red[tid] = dv * dv;
    __syncthreads();
    if (tid < 64) {
        float s = red[tid] + red[tid + 64];
        #pragma unroll
        for (int m = 1; m < 64; m <<= 1) s += __shfl_xor(s, m);
        if (tid == 0) red[0] = s;
    }
    __syncthreads();
    float rstd = rsqrtf(red[0] * (1.0f / HID) + 1e-5f);

    nrm[(size_t)(t * N + dst) * HID + tid] = dv * rstd * g1[tid] + be1[tid];
    if (t == T - 1) xlast_g[(size_t)dst * HID + tid] = v;
}

// tiled qkv GEMM over nrm rows: blocks [0,1250) compute k|v for all T*N rows
// (kv[row][0..127]=k, [128..255]=v); blocks [1250,1407) compute q for the
// last-t rows only (qlast[n][0..127]). Bias folded in. 32-row register tile:
// one float4 weight load feeds 16 FMAs, weights reused across 32 rows.
__global__ __launch_bounds__(256) void k_qkv(const float* __restrict__ nrm,
                                             const float* __restrict__ WTq,
                                             const float* __restrict__ b_qkv,
                                             float* __restrict__ kv,
                                             float* __restrict__ qlast) {
    __shared__ float at[MT][HID];
    const int NKV = (T * N) / MT;   // 1250
    int b = blockIdx.x;
    int tid = threadIdx.x;
    bool qp = (b >= NKV);
    int row0 = qp ? (b - NKV) * MT : b * MT;
    const float* src = qp ? nrm + (size_t)(T - 1) * N * HID : nrm;
    int rmax = qp ? N : T * N;

    for (int idx = tid; idx < MT * HID; idx += 256) {
        int r = idx >> 7, c = idx & 127;
        int row = row0 + r;
        at[r][c] = (row < rmax) ? src[(size_t)row * HID + c] : 0.0f;
    }
    __syncthreads();

    int cg = tid & 31, rg = tid >> 5;
    int c0 = cg * 4, r0 = rg * 4;

    int gb = qp ? 0 : 1, ge = qp ? 1 : 3;
    for (int g = gb; g < ge; ++g) {
        int co = g * 128 + c0;
        float4 b4 = *(const float4*)(b_qkv + co);
        float a00=b4.x,a01=b4.y,a02=b4.z,a03=b4.w;
        float a10=b4.x,a11=b4.y,a12=b4.z,a13=b4.w;
        float a20=b4.x,a21=b4.y,a22=b4.z,a23=b4.w;
        float a30=b4.x,a31=b4.y,a32=b4.z,a33=b4.w;
        for (int k = 0; k < HID; ++k) {
            float4 w = *(const float4*)(WTq + (size_t)k * 384 + co);
            float e0 = at[r0 + 0][k], e1 = at[r0 + 1][k];
            float e2 = at[r0 + 2][k], e3 = at[r0 + 3][k];
            a00 += e0*w.x; a01 += e0*w.y; a02 += e0*w.z; a03 += e0*w.w;
            a10 += e1*w.x; a11 += e1*w.y; a12 += e1*w.z; a13 += e1*w.w;
            a20 += e2*w.x; a21 += e2*w.y; a22 += e2*w.z; a23 += e2*w.w;
            a30 += e3*w.x; a31 += e3*w.y; a32 += e3*w.z; a33 += e3*w.w;
        }
        float4 v0; v0.x=a00; v0.y=a01; v0.z=a02; v0.w=a03;
        float4 v1; v1.x=a10; v1.y=a11; v1.z=a12; v1.w=a13;
        float4 v2; v2.x=a20; v2.y=a21; v2.z=a22; v2.w=a23;
        float4 v3; v3.x=a30; v3.y=a31; v3.z=a32; v3.w=a33;
        if (qp) {
            if (row0 + r0 + 0 < N) *(float4*)(qlast + (size_t)(row0+r0+0) * HID + c0) = v0;
            if (row0 + r0 + 1 < N) *(float4*)(qlast + (size_t)(row0+r0+1) * HID + c0) = v1;
            if (row0 + r0 + 2 < N) *(float4*)(qlast + (size_t)(row0+r0+2) * HID + c0) = v2;
            if (row0 + r0 + 3 < N) *(float4*)(qlast + (size_t)(row0+r0+3) * HID + c0) = v3;
        } else {
            int coff = (g - 1) * 128 + c0;
            *(float4*)(kv + (size_t)(row0+r0+0) * 256 + coff) = v0;
            *(float4*)(kv + (size_t)(row0+r0+1) * 256 + coff) = v1;
            *(float4*)(kv + (size_t)(row0+r0+2) * 256 + coff) = v2;
            *(float4*)(kv + (size_t)(row0+r0+3) * 256 + coff) = v3;
        }
    }
}

// per-node (slim): load k/v/q/xlast -> attention -> W_o -> LN2 -> out
__global__ __launch_bounds__(128) void k_node(
        const float* __restrict__ kv, const float* __restrict__ qlast,
        const float* __restrict__ xlast_g,
        const float* __restrict__ WoT, const float* __restrict__ b_o,
        const float* __restrict__ g2, const float* __restrict__ be2,
        const float* __restrict__ noise, float* __restrict__ out) {
    __shared__ float ql[HID];
    __shared__ float kl[H][T][D];
    __shared__ float vl[H][T][D];
    __shared__ float attn_l[H][T];
    __shared__ float ta[HID];
    __shared__ float red[128];

    int n = blockIdx.x;
    int tid = threadIdx.x;
    int hh = tid >> 4, dd = tid & 15;

    ql[tid] = qlast[(size_t)n * HID + tid];
    #pragma unroll
    for (int tt = 0; tt < T; ++tt) {
        const float* kvr = kv + (size_t)(tt * N + n) * 256;
        kl[hh][tt][dd] = kvr[tid];
        vl[hh][tt][dd] = kvr[128 + tid];
    }
    float xl = xlast_g[(size_t)n * HID + tid];
    __syncthreads();

    if (tid < H) {
        int hq = tid;
        float sc[T];
        float mx = -1e30f;
        #pragma unroll
        for (int tk = 0; tk < T; ++tk) {
            float a = 0.0f;
            #pragma unroll
            for (int d2 = 0; d2 < D; ++d2) a += ql[hq * D + d2] * kl[hq][tk][d2];
            a *= 0.25f;
            sc[tk] = a;
            mx = fmaxf(mx, a);
        }
        float ssum = 0.0f;
        #pragma unroll
        for (int tk = 0; tk < T; ++tk) { sc[tk] = expf(sc[tk] - mx); ssum += sc[tk]; }
        float inv = 1.0f / ssum;
        #pragma unroll
        for (int tk = 0; tk < T; ++tk) attn_l[hq][tk] = sc[tk] * inv;
    }
    __syncthreads();

    {
        float a = 0.0f;
        #pragma unroll
        for (int tk = 0; tk < T; ++tk) a += attn_l[hh][tk] * vl[hh][tk][dd];
        ta[tid] = a;
    }
    __syncthreads();

    // W_o + residual
    float o = b_o[tid];
    #pragma unroll 8
    for (int k = 0; k < HID; k += 4) {
        float4 t4 = *(const float4*)&ta[k];
        o += t4.x * WoT[(size_t)(k + 0) * 128 + tid]
           + t4.y * WoT[(size_t)(k + 1) * 128 + tid]
           + t4.z * WoT[(size_t)(k + 2) * 128 + tid]
           + t4.w * WoT[(size_t)(k + 3) * 128 + tid];
    }
    float x2 = xl + o;

    red[tid] = x2;
    __syncthreads();
    if (tid < 64) {
        float s = red[tid] + red[tid + 64];
        #pragma unroll
        for (int m = 1; m < 64; m <<= 1) s += __shfl_xor(s, m);
        if (tid == 0) red[0] = s;
    }
    __syncthreads();
    float mu2 = red[0] * (1.0f / HID);
    __syncthreads();
    float d2v = x2 - mu2;
    red[tid] = d2v * d2v;
    __syncthreads();
    if (tid < 64) {
        float s = red[tid] + red[tid + 64];
        #pragma unroll
        for (int m = 1; m < 64; m <<= 1) s += __shfl_xor(s, m);
        if (tid == 0) red[0] = s;
    }
    __syncthreads();
    float rstd2 = rsqrtf(red[0] * (1.0f / HID) + 1e-5f);

    float div = sinf(((float)n / (float)N) * 6.28f) * 0.1f;
    float emb = d2v * rstd2 * g2[tid] + be2[tid]
              + div + noise[(size_t)n * HID + tid] * 0.05f;
    out[(size_t)n * HID + tid] = emb;
}

// classifier: tiled h1 = emb@Wc1 + bc1 -> LN3 -> gelu -> logits
__global__ __launch_bounds__(256) void k_cls(const float* __restrict__ emb,
                                             const float* __restrict__ Wc1,
                                             const float* __restrict__ bc1,
                                             const float* __restrict__ gc,
                                             const float* __restrict__ bec,
                                             const float* __restrict__ Wc2,
                                             const float* __restrict__ bc2,
                                             float* __restrict__ out) {
    __shared__ float et[MT][HID];
    __shared__ float h1t[MT][HID + 1];
    int row0 = blockIdx.x * MT;
    int tid = threadIdx.x;

    for (int idx = tid; idx < MT * HID; idx += 256) {
        int r = idx >> 7, c = idx & 127;
        int row = row0 + r;
        et[r][c] = (row < N) ? emb[(size_t)row * HID + c] : 0.0f;
    }
    __syncthreads();

    {
        int cg = tid & 31, rg = tid >> 5;
        int c0 = cg * 4, r0 = rg * 4;
        float4 b4 = *(const float4*)(bc1 + c0);
        float a00=b4.x,a01=b4.y,a02=b4.z,a03=b4.w;
        float a10=b4.x,a11=b4.y,a12=b4.z,a13=b4.w;
        float a20=b4.x,a21=b4.y,a22=b4.z,a23=b4.w;
        float a30=b4.x,a31=b4.y,a32=b4.z,a33=b4.w;
        for (int k = 0; k < HID; ++k) {
            float4 w = *(const float4*)(Wc1 + (size_t)k * HID + c0);
            float e0 = et[r0 + 0][k], e1 = et[r0 + 1][k];
            float e2 = et[r0 + 2][k], e3 = et[r0 + 3][k];
            a00 += e0*w.x; a01 += e0*w.y; a02 += e0*w.z; a03 += e0*w.w;
            a10 += e1*w.x; a11 += e1*w.y; a12 += e1*w.z; a13 += e1*w.w;
            a20 += e2*w.x; a21 += e2*w.y; a22 += e2*w.z; a23 += e2*w.w;
            a30 += e3*w.x; a31 += e3*w.y; a32 += e3*w.z; a33 += e3*w.w;
        }
        h1t[r0+0][c0+0]=a00; h1t[r0+0][c0+1]=a01; h1t[r0+0][c0+2]=a02; h1t[r0+0][c0+3]=a03;
        h1t[r0+1][c0+0]=a10; h1t[r0+1][c0+1]=a11; h1t[r0+1][c0+2]=a12; h1t[r0+1][c0+3]=a13;
        h1t[r0+2][c0+0]=a20; h1t[r0+2][c0+1]=a21; h1t[r0+2][c0+2]=a22; h1t[r0+2][c0+3]=a23;
        h1t[r0+3][c0+0]=a30; h1t[r0+3][c0+1]=a31; h1t[r0+3][c0+2]=a32; h1t[r0+3][c0+3]=a33;
    }
    __syncthreads();

    // LN3 + gelu: 8 lanes per row (32 rows x 8 = 256 threads)
    {
        int r = tid >> 3, l = tid & 7;
        float p = 0.0f;
        #pragma unroll
        for (int k = 0; k < 16; ++k) p += h1t[r][l + 8 * k];
        #pragma unroll
        for (int m = 1; m < 8; m <<= 1) p += __shfl_xor(p, m);
        float mu = p * (1.0f / HID);
        float v = 0.0f;
        #pragma unroll
        for (int k = 0; k < 16; ++k) { float d = h1t[r][l + 8 * k] - mu; v += d * d; }
        #pragma unroll
        for (int m = 1; m < 8; m <<= 1) v += __shfl_xor(v, m);
        float rstd = rsqrtf(v * (1.0f / HID) + 1e-5f);
        #pragma unroll
        for (int k = 0; k < 16; ++k) {
            int c = l + 8 * k;
            float lnv = (h1t[r][c] - mu) * rstd * gc[c] + bec[c];
            h1t[r][c] = 0.5f * lnv * (1.0f + erff(lnv * 0.70710678118f));
        }
    }
    __syncthreads();

    // logits: 64 outputs (32 rows x 2)
    if (tid < MT * NC) {
        int r = tid >> 1, j = tid & 1;
        int row = row0 + r;
        if (row < N) {
            float acc = bc2[j];
            #pragma unroll 8
            for (int c = 0; c < HID; ++c) acc += h1t[r][c] * Wc2[c * NC + j];
            if (j == 1) acc += sinf((float)row * 0.5f) * 0.2f;
            out[(size_t)N * HID + (size_t)row * NC + j] = acc;
        }
    }
}

extern "C" void kernel_launch(void* const* d_in, const int* in_sizes, int n_in,
                              void* d_out, int out_size, void* d_ws, size_t ws_size,
                              hipStream_t stream) {
    const float* x      = (const float*)d_in[0];
    const int*   ei     = (const int*)d_in[1];
    const float* noise  = (const float*)d_in[2];
    const float* W_proj = (const float*)d_in[3];
    const float* b_proj = (const float*)d_in[4];
    const float* W_gat  = (const float*)d_in[5];
    const float* a_src  = (const float*)d_in[6];
    const float* a_dst  = (const float*)d_in[7];
    const float* b_gat  = (const float*)d_in[8];
    const float* g1     = (const float*)d_in[9];
    const float* be1    = (const float*)d_in[10];
    const float* W_qkv  = (const float*)d_in[11];
    const float* b_qkv  = (const float*)d_in[12];
    const float* W_o    = (const float*)d_in[13];
    const float* b_o    = (const float*)d_in[14];
    const float* g2     = (const float*)d_in[15];
    const float* be2    = (const float*)d_in[16];
    const float* Wc1    = (const float*)d_in[17];
    const float* bc1    = (const float*)d_in[18];
    const float* gc     = (const float*)d_in[19];
    const float* bec    = (const float*)d_in[20];
    const float* Wc2    = (const float*)d_in[21];
    const float* bc2    = (const float*)d_in[22];
    float* out = (float*)d_out;

    float* xh     = (float*)d_ws;                  //  5,120,000
    float* nrm    = xh + 5120000;                  //  5,120,000
    float* a_s    = nrm + 5120000;                 //    320,000
    float* a_d    = a_s + 320000;                  //    320,000
    int*   offs    = (int*)(a_d + 320000);         //     40,008
    int*   cursor  = offs + 40008;                 //     40,000
    int*   csr_src = cursor + 40000;               //  1,320,000
    float* WTq    = (float*)(csr_src + 1320000);   //     49,152
    float* WoT    = WTq + 49152;                   //     16,384
    float* kv     = WoT + 16384;                   // 10,240,000
    float* qlast  = kv + 10240000;                 //    640,000
    float* xlastg = qlast + 640000;                //    640,000

    k_tr<<<(384 * 128 + 128 * 128 + 255) / 256, 256, 0, stream>>>(W_qkv, W_o, WTq, WoT);

    k_pg<<<T * N / MT, 256, 0, stream>>>(x, W_proj, b_proj, W_gat, a_src, a_dst,
                                         xh, a_s, a_d, cursor);

    k_hist<<<T * 8, 256, 0, stream>>>(ei, cursor);
    k_scan<<<T, 256, 0, stream>>>(cursor, offs);
    k_scatter<<<(T * (EN / 4) + 255) / 256, 256, 0, stream>>>(ei, cursor, csr_src);

    k_aggc<<<T * N, 128, 0, stream>>>(offs, csr_src, a_s, a_d, xh,
                                      b_gat, g1, be1, nrm, xlastg);

    k_qkv<<<(T * N) / MT + (N + MT - 1) / MT, 256, 0, stream>>>(nrm, WTq, b_qkv,
                                                                kv, qlast);

    k_node<<<N, 128, 0, stream>>>(kv, qlast, xlastg, WoT, b_o,
                                  g2, be2, noise, out);

    k_cls<<<(N + MT - 1) / MT, 256, 0, stream>>>(out, Wc1, bc1, gc, bec, Wc2, bc2, out);
}

// Round 6
// 383.549 us; speedup vs baseline: 1.2096x; 1.0258x over previous
//
#include <hip/hip_runtime.h>
#include <math.h>

#define T 8
#define N 5000
#define E 160000
#define EN (E + N)
#define IN_DIM 64
#define HID 128
#define H 8
#define D 16
#define NC 2
#define MT 32            // rows per tiled-GEMM block
#define NB 4             // nodes per k_fuse block

__device__ __forceinline__ float leaky(float e) { return (e >= 0.0f) ? e : 0.2f * e; }

// fused h=relu(x@Wp+bp); xh=h@Wg; a_s/a_d coef epilogue. Also zeroes cursor.
__global__ __launch_bounds__(256) void k_pg(const float* __restrict__ x,
                                            const float* __restrict__ Wp,
                                            const float* __restrict__ bp,
                                            const float* __restrict__ Wg,
                                            const float* __restrict__ asrc,
                                            const float* __restrict__ adst,
                                            float* __restrict__ xh,
                                            float* __restrict__ a_s,
                                            float* __restrict__ a_d,
                                            int* __restrict__ cursor) {
    __shared__ float xt[MT][IN_DIM];
    __shared__ float ht[MT][HID + 1];
    int row0 = blockIdx.x * MT;
    int tid = threadIdx.x;

    {   // fold the cursor memset into this kernel (runs before k_hist)
        int gi = blockIdx.x * 256 + tid;
        if (gi < T * N) cursor[gi] = 0;
    }

    for (int idx = tid; idx < MT * IN_DIM; idx += 256) {
        int r = idx >> 6, k = idx & 63;
        xt[r][k] = x[(size_t)(row0 + r) * IN_DIM + k];
    }
    __syncthreads();

    int cg = tid & 31;
    int rg = tid >> 5;
    int c0 = cg * 4, r0 = rg * 4;

    {
        float4 b4 = *(const float4*)(bp + c0);
        float a00=b4.x,a01=b4.y,a02=b4.z,a03=b4.w;
        float a10=b4.x,a11=b4.y,a12=b4.z,a13=b4.w;
        float a20=b4.x,a21=b4.y,a22=b4.z,a23=b4.w;
        float a30=b4.x,a31=b4.y,a32=b4.z,a33=b4.w;
        for (int k = 0; k < IN_DIM; ++k) {
            float4 w = *(const float4*)(Wp + (size_t)k * HID + c0);
            float x0 = xt[r0 + 0][k], x1 = xt[r0 + 1][k];
            float x2 = xt[r0 + 2][k], x3 = xt[r0 + 3][k];
            a00 += x0*w.x; a01 += x0*w.y; a02 += x0*w.z; a03 += x0*w.w;
            a10 += x1*w.x; a11 += x1*w.y; a12 += x1*w.z; a13 += x1*w.w;
            a20 += x2*w.x; a21 += x2*w.y; a22 += x2*w.z; a23 += x2*w.w;
            a30 += x3*w.x; a31 += x3*w.y; a32 += x3*w.z; a33 += x3*w.w;
        }
        ht[r0+0][c0+0]=fmaxf(a00,0.f); ht[r0+0][c0+1]=fmaxf(a01,0.f);
        ht[r0+0][c0+2]=fmaxf(a02,0.f); ht[r0+0][c0+3]=fmaxf(a03,0.f);
        ht[r0+1][c0+0]=fmaxf(a10,0.f); ht[r0+1][c0+1]=fmaxf(a11,0.f);
        ht[r0+1][c0+2]=fmaxf(a12,0.f); ht[r0+1][c0+3]=fmaxf(a13,0.f);
        ht[r0+2][c0+0]=fmaxf(a20,0.f); ht[r0+2][c0+1]=fmaxf(a21,0.f);
        ht[r0+2][c0+2]=fmaxf(a22,0.f); ht[r0+2][c0+3]=fmaxf(a23,0.f);
        ht[r0+3][c0+0]=fmaxf(a30,0.f); ht[r0+3][c0+1]=fmaxf(a31,0.f);
        ht[r0+3][c0+2]=fmaxf(a32,0.f); ht[r0+3][c0+3]=fmaxf(a33,0.f);
    }
    __syncthreads();

    float a00=0,a01=0,a02=0,a03=0, a10=0,a11=0,a12=0,a13=0;
    float a20=0,a21=0,a22=0,a23=0, a30=0,a31=0,a32=0,a33=0;
    for (int k = 0; k < HID; ++k) {
        float4 w = *(const float4*)(Wg + (size_t)k * HID + c0);
        float h0 = ht[r0 + 0][k], h1 = ht[r0 + 1][k];
        float h2 = ht[r0 + 2][k], h3 = ht[r0 + 3][k];
        a00 += h0*w.x; a01 += h0*w.y; a02 += h0*w.z; a03 += h0*w.w;
        a10 += h1*w.x; a11 += h1*w.y; a12 += h1*w.z; a13 += h1*w.w;
        a20 += h2*w.x; a21 += h2*w.y; a22 += h2*w.z; a23 += h2*w.w;
        a30 += h3*w.x; a31 += h3*w.y; a32 += h3*w.z; a33 += h3*w.w;
    }
    {
        float4 v;
        v.x=a00; v.y=a01; v.z=a02; v.w=a03;
        *(float4*)(xh + (size_t)(row0 + r0 + 0) * HID + c0) = v;
        v.x=a10; v.y=a11; v.z=a12; v.w=a13;
        *(float4*)(xh + (size_t)(row0 + r0 + 1) * HID + c0) = v;
        v.x=a20; v.y=a21; v.z=a22; v.w=a23;
        *(float4*)(xh + (size_t)(row0 + r0 + 2) * HID + c0) = v;
        v.x=a30; v.y=a31; v.z=a32; v.w=a33;
        *(float4*)(xh + (size_t)(row0 + r0 + 3) * HID + c0) = v;
    }
    __syncthreads();
    ht[r0+0][c0+0]=a00; ht[r0+0][c0+1]=a01; ht[r0+0][c0+2]=a02; ht[r0+0][c0+3]=a03;
    ht[r0+1][c0+0]=a10; ht[r0+1][c0+1]=a11; ht[r0+1][c0+2]=a12; ht[r0+1][c0+3]=a13;
    ht[r0+2][c0+0]=a20; ht[r0+2][c0+1]=a21; ht[r0+2][c0+2]=a22; ht[r0+2][c0+3]=a23;
    ht[r0+3][c0+0]=a30; ht[r0+3][c0+1]=a31; ht[r0+3][c0+2]=a32; ht[r0+3][c0+3]=a33;
    __syncthreads();

    {
        int r = tid >> 3, hh = tid & 7;
        float s1 = 0.0f, s2 = 0.0f;
        #pragma unroll
        for (int d = 0; d < D; ++d) {
            float v = ht[r][hh * D + d];
            s1 += v * asrc[hh * D + d];
            s2 += v * adst[hh * D + d];
        }
        a_s[(size_t)(row0 + r) * H + hh] = s1;
        a_d[(size_t)(row0 + r) * H + hh] = s2;
    }
}

// transpose W_qkv (384x128 -> 128x384) and W_o (128x128 -> 128x128)
__global__ void k_tr(const float* __restrict__ W_qkv, const float* __restrict__ W_o,
                     float* __restrict__ WTq, float* __restrict__ WoT) {
    int idx = blockIdx.x * 256 + threadIdx.x;
    if (idx < 384 * 128) {
        int j = idx >> 7, c = idx & 127;
        WTq[c * 384 + j] = W_qkv[idx];
    } else if (idx < 384 * 128 + 128 * 128) {
        int r = idx - 384 * 128;
        int j = r >> 7, k = r & 127;
        WoT[k * 128 + j] = W_o[r];
    }
}

// LDS-privatized degree histogram: T*8 blocks, each histograms ~EN/8 edges
// of one t into LDS, then flushes 5000 coalesced global atomics.
__global__ __launch_bounds__(256) void k_hist(const int* __restrict__ ei,
                                              int* __restrict__ cursor) {
    __shared__ int hist[N];          // 20 KB
    int t = blockIdx.x >> 3;
    int chunk = blockIdx.x & 7;
    int tid = threadIdx.x;

    for (int i = tid; i < N; i += 256) hist[i] = 0;
    __syncthreads();

    const int CS = (EN + 7) / 8;     // 20625
    int i0 = chunk * CS;
    int i1 = (i0 + CS < EN) ? i0 + CS : EN;
    const int* drow = ei + (size_t)(2 * t + 1) * E;
    for (int i = i0 + tid; i < i1; i += 256) {
        int d = (i < E) ? drow[i] : (i - E);
        atomicAdd(&hist[d], 1);
    }
    __syncthreads();

    int* cur = cursor + t * N;
    for (int i = tid; i < N; i += 256) {
        int c = hist[i];
        if (c) atomicAdd(&cur[i], c);
    }
}

__global__ void k_scan(int* __restrict__ cursor, int* __restrict__ offs) {
    __shared__ int part[256];
    int t = blockIdx.x;
    int tid = threadIdx.x;
    const int CH = 20;
    int begin = tid * CH;
    int sum = 0;
    for (int k = 0; k < CH; ++k) {
        int i = begin + k;
        if (i < N) sum += cursor[t * N + i];
    }
    part[tid] = sum;
    __syncthreads();
    if (tid == 0) {
        int run = 0;
        for (int i = 0; i < 256; ++i) { int v = part[i]; part[i] = run; run += v; }
        offs[t * (N + 1) + N] = run;
    }
    __syncthreads();
    int run = part[tid];
    for (int k = 0; k < CH; ++k) {
        int i = begin + k;
        if (i < N) {
            int cnt = cursor[t * N + i];
            offs[t * (N + 1) + i] = run;
            cursor[t * N + i] = run;
            run += cnt;
        }
    }
}

// scatter with 4-edge ILP per thread (strided within one t for coalescing):
// 4 independent atomic chains per thread hide atomic latency.
__global__ __launch_bounds__(256) void k_scatter(const int* __restrict__ ei,
                                                 int* __restrict__ cursor,
                                                 int* __restrict__ csr_src) {
    const int PT = EN / 4;           // 41250 threads per t
    int idx = blockIdx.x * 256 + threadIdx.x;
    int t = idx / PT;
    if (t >= T) return;
    int e0 = idx - t * PT;

    const int* srow = ei + (size_t)(2 * t) * E;
    const int* drow = srow + E;
    int s[4], d[4];
    #pragma unroll
    for (int j = 0; j < 4; ++j) {
        int i = e0 + j * PT;
        if (i < E) { s[j] = srow[i]; d[j] = drow[i]; }
        else       { s[j] = d[j] = i - E; }
    }
    int* cur = cursor + t * N;
    int p[4];
    #pragma unroll
    for (int j = 0; j < 4; ++j) p[j] = atomicAdd(&cur[d[j]], 1);
    int* csb = csr_src + (size_t)t * EN;
    #pragma unroll
    for (int j = 0; j < 4; ++j) csb[p[j]] = s[j];
}

// GAT aggregation + fused LN1, one block per (dst,t), atomic-free.
// Single-pass softmax. Writes nrm in NODE-MAJOR layout [n][t][c] so the
// downstream fused attention kernel sees 32 contiguous rows per 4 nodes.
__global__ __launch_bounds__(128) void k_aggc(
        const int* __restrict__ offs, const int* __restrict__ csr_src,
        const float* __restrict__ a_s, const float* __restrict__ a_d,
        const float* __restrict__ xh, const float* __restrict__ b_gat,
        const float* __restrict__ g1, const float* __restrict__ be1,
        float* __restrict__ nrm, float* __restrict__ xlast_g) {
    int b = blockIdx.x;
    int t = b & 7;            // T == 8
    int dst = b >> 3;
    int tid = threadIdx.x;

    int o0 = offs[t * (N + 1) + dst];
    int o1 = offs[t * (N + 1) + dst + 1];
    int deg = o1 - o0;
    const int* esrc = csr_src + (size_t)t * EN + o0;
    const float* as_b = a_s + (size_t)t * N * H;
    const float* ad_b = a_d + (size_t)t * N * H;
    const float* xh_b = xh + (size_t)t * N * HID;

    __shared__ float lal[16][H];     // per-tile weights
    __shared__ int   lsrc[16];
    __shared__ float ws_s[2][H];     // per-wave wsum partials
    __shared__ float pacc[2][HID];   // per-wave acc partials
    __shared__ float red[128];

    int eh_e = tid >> 3, eh_h = tid & 7;   // lal-compute mapping
    int el = tid >> 5, cg = tid & 31;      // gather mapping
    int hg = cg >> 2;
    float adh_e = ad_b[dst * H + eh_h];

    float4 acc = {0.0f, 0.0f, 0.0f, 0.0f};
    float wpart = 0.0f;

    int ntile = (deg + 15) >> 4;
    for (int tt = 0; tt < ntile; ++tt) {
        int ej = (tt << 4) + eh_e;
        float w = 0.0f;
        int src = 0;
        if (ej < deg) {
            src = esrc[ej];
            w = expf(leaky(as_b[src * H + eh_h] + adh_e));
        }
        if (eh_h == 0) lsrc[eh_e] = src;
        lal[eh_e][eh_h] = w;
        wpart += w;
        __syncthreads();
        #pragma unroll
        for (int jj = 0; jj < 4; ++jj) {
            int j = (jj << 2) + el;
            int s = lsrc[j];
            float l = lal[j][hg];
            float4 v = *(const float4*)(xh_b + (size_t)s * HID + (cg << 2));
            acc.x += l * v.x; acc.y += l * v.y;
            acc.z += l * v.z; acc.w += l * v.w;
        }
        __syncthreads();
    }

    // reduce wsum over edge-slots
    {
        float w = wpart;
        w += __shfl_xor(w, 8);
        w += __shfl_xor(w, 16);
        w += __shfl_xor(w, 32);
        if ((tid & 63) < 8) ws_s[tid >> 6][eh_h] = w;
    }
    // reduce acc over edge-lanes
    acc.x += __shfl_xor(acc.x, 32);
    acc.y += __shfl_xor(acc.y, 32);
    acc.z += __shfl_xor(acc.z, 32);
    acc.w += __shfl_xor(acc.w, 32);
    if (!(tid & 32)) *(float4*)&pacc[tid >> 6][(tid & 31) << 2] = acc;
    __syncthreads();

    int hh = tid >> 4;
    float wsum = ws_s[0][hh] + ws_s[1][hh];
    float val = (pacc[0][tid] + pacc[1][tid]) / (wsum + 1e-16f);

    // ---- fused LN1 over this (t,dst) row ----
    float v = val + b_gat[tid];
    red[tid] = v;
    __syncthreads();
    if (tid < 64) {
        float s = red[tid] + red[tid + 64];
        #pragma unroll
        for (int m = 1; m < 64; m <<= 1) s += __shfl_xor(s, m);
        if (tid == 0) red[0] = s;
    }
    __syncthreads();
    float mu = red[0] * (1.0f / HID);
    __syncthreads();
    float dv = v - mu;
    red[tid] = dv * dv;
    __syncthreads();
    if (tid < 64) {
        float s = red[tid] + red[tid + 64];
        #pragma unroll
        for (int m = 1; m < 64; m <<= 1) s += __shfl_xor(s, m);
        if (tid == 0) red[0] = s;
    }
    __syncthreads();
    float rstd = rsqrtf(red[0] * (1.0f / HID) + 1e-5f);

    // node-major write
    nrm[(size_t)(dst * T + t) * HID + tid] = dv * rstd * g1[tid] + be1[tid];
    if (t == T - 1) xlast_g[(size_t)dst * HID + tid] = v;
}

// fused qkv GEMM + attention + W_o + LN2 + epilogue for NB=4 nodes/block.
// 32 contiguous nrm rows (4 nodes x 8 t) -> tiled k|v GEMM into LDS (no HBM
// round-trip), q for last-t rows, shfl-softmax scores, PV, W_o, wave-LN2.
__global__ __launch_bounds__(256) void k_fuse(
        const float* __restrict__ nrm,      // [N*T][HID] node-major
        const float* __restrict__ WTq,      // [128][384]
        const float* __restrict__ b_qkv,
        const float* __restrict__ xlast_g,
        const float* __restrict__ WoT,
        const float* __restrict__ b_o,
        const float* __restrict__ g2, const float* __restrict__ be2,
        const float* __restrict__ noise, float* __restrict__ out) {
    __shared__ float at[NB * T][HID];           // 16 KB; rows 0..5 reused post-q
    __shared__ float kvl[2][NB * T][HID + 2];   // 33.3 KB, stride 130
    __shared__ float ql[NB][HID];               // 2 KB
    float* attn_s = &at[0][0];          // [NB][H][T] = 256 floats (alias)
    float* ta_s   = &at[0][0] + 256;    // [NB][HID]  = 512 floats (alias)

    int n0 = blockIdx.x * NB;
    int tid = threadIdx.x;

    // load 32 rows of nrm (coalesced float4)
    {
        const float* src = nrm + (size_t)n0 * T * HID;
        for (int idx = tid; idx < NB * T * 32; idx += 256) {
            int r = idx >> 5, c4 = (idx & 31) << 2;
            *(float4*)&at[r][c4] = *(const float4*)(src + (size_t)r * HID + c4);
        }
    }
    __syncthreads();

    int cg = tid & 31, rg = tid >> 5;
    int c0 = cg * 4, r0 = rg * 4;

    // k,v GEMM: 32 rows x 128 cols each, results stay in LDS
    #pragma unroll
    for (int g = 0; g < 2; ++g) {
        int co = 128 + g * 128 + c0;
        float4 b4 = *(const float4*)(b_qkv + co);
        float a00=b4.x,a01=b4.y,a02=b4.z,a03=b4.w;
        float a10=b4.x,a11=b4.y,a12=b4.z,a13=b4.w;
        float a20=b4.x,a21=b4.y,a22=b4.z,a23=b4.w;
        float a30=b4.x,a31=b4.y,a32=b4.z,a33=b4.w;
        for (int k = 0; k < HID; ++k) {
            float4 w = *(const float4*)(WTq + (size_t)k * 384 + co);
            float e0 = at[r0+0][k], e1 = at[r0+1][k];
            float e2 = at[r0+2][k], e3 = at[r0+3][k];
            a00 += e0*w.x; a01 += e0*w.y; a02 += e0*w.z; a03 += e0*w.w;
            a10 += e1*w.x; a11 += e1*w.y; a12 += e1*w.z; a13 += e1*w.w;
            a20 += e2*w.x; a21 += e2*w.y; a22 += e2*w.z; a23 += e2*w.w;
            a30 += e3*w.x; a31 += e3*w.y; a32 += e3*w.z; a33 += e3*w.w;
        }
        kvl[g][r0+0][c0+0]=a00; kvl[g][r0+0][c0+1]=a01; kvl[g][r0+0][c0+2]=a02; kvl[g][r0+0][c0+3]=a03;
        kvl[g][r0+1][c0+0]=a10; kvl[g][r0+1][c0+1]=a11; kvl[g][r0+1][c0+2]=a12; kvl[g][r0+1][c0+3]=a13;
        kvl[g][r0+2][c0+0]=a20; kvl[g][r0+2][c0+1]=a21; kvl[g][r0+2][c0+2]=a22; kvl[g][r0+2][c0+3]=a23;
        kvl[g][r0+3][c0+0]=a30; kvl[g][r0+3][c0+1]=a31; kvl[g][r0+3][c0+2]=a32; kvl[g][r0+3][c0+3]=a33;
    }

    // q for last-t row of each node (wave u handles node u; at row broadcast)
    {
        int u = tid >> 6, c = tid & 63;
        float q0 = b_qkv[c], q1 = b_qkv[c + 64];
        const float* ar = at[u * T + (T - 1)];
        for (int k = 0; k < HID; ++k) {
            float av = ar[k];
            q0 += av * WTq[(size_t)k * 384 + c];
            q1 += av * WTq[(size_t)k * 384 + c + 64];
        }
        ql[u][c] = q0;
        ql[u][c + 64] = q1;
    }
    __syncthreads();

    // scores + softmax: thread -> (u, h, tk); softmax over tk = 8-lane shfl
    {
        int u = tid >> 6, h = (tid >> 3) & 7, tk = tid & 7;
        float qf[D];
        #pragma unroll
        for (int d = 0; d < D; ++d) qf[d] = ql[u][h * D + d];
        const float* kr = &kvl[0][u * T + tk][h * D];
        float a = 0.0f;
        #pragma unroll
        for (int d = 0; d < D; ++d) a += qf[d] * kr[d];
        a *= 0.25f;                 // 1/sqrt(D)
        float mx = a;
        mx = fmaxf(mx, __shfl_xor(mx, 1));
        mx = fmaxf(mx, __shfl_xor(mx, 2));
        mx = fmaxf(mx, __shfl_xor(mx, 4));
        float w = expf(a - mx);
        float ssum = w;
        ssum += __shfl_xor(ssum, 1);
        ssum += __shfl_xor(ssum, 2);
        ssum += __shfl_xor(ssum, 4);
        attn_s[u * 64 + h * 8 + tk] = w / ssum;   // alias: at rows 0-1 (dead)
    }
    __syncthreads();

    // PV: thread -> (u, c) x2; vl reads stride-1 (conflict-free)
    {
        int u = tid >> 6, c = tid & 63;
        int ha = c >> 4, hb = (c + 64) >> 4;
        const float* aa = attn_s + u * 64 + ha * 8;
        const float* ab = attn_s + u * 64 + hb * 8;
        float sa = 0.0f, sb = 0.0f;
        #pragma unroll
        for (int tk = 0; tk < T; ++tk) {
            const float* vr = kvl[1][u * T + tk];
            sa += aa[tk] * vr[c];
            sb += ab[tk] * vr[c + 64];
        }
        ta_s[u * 128 + c] = sa;          // alias: at rows 2-5 (disjoint)
        ta_s[u * 128 + c + 64] = sb;
    }
    __syncthreads();

    // W_o + residual + LN2 (wave == node, pure shfl) + epilogue
    {
        int u = tid >> 6, c = tid & 63;
        int n = n0 + u;
        float o0 = b_o[c], o1 = b_o[c + 64];
        const float* tar = ta_s + u * 128;
        #pragma unroll 8
        for (int k = 0; k < HID; k += 4) {
            float t0 = tar[k], t1 = tar[k+1], t2 = tar[k+2], t3 = tar[k+3];
            o0 += t0 * WoT[(size_t)(k+0)*128 + c]  + t1 * WoT[(size_t)(k+1)*128 + c]
                + t2 * WoT[(size_t)(k+2)*128 + c]  + t3 * WoT[(size_t)(k+3)*128 + c];
            o1 += t0 * WoT[(size_t)(k+0)*128 + c+64] + t1 * WoT[(size_t)(k+1)*128 + c+64]
                + t2 * WoT[(size_t)(k+2)*128 + c+64] + t3 * WoT[(size_t)(k+3)*128 + c+64];
        }
        float xa = xlast_g[(size_t)n * HID + c];
        float xb = xlast_g[(size_t)n * HID + c + 64];
        float x2a = xa + o0, x2b = xb + o1;
        float s = x2a + x2b, qs = x2a * x2a + x2b * x2b;
        #pragma unroll
        for (int m = 1; m < 64; m <<= 1) {
            s  += __shfl_xor(s, m);
            qs += __shfl_xor(qs, m);
        }
        float mu = s * (1.0f / HID);
        float var = qs * (1.0f / HID) - mu * mu;
        float rstd = rsqrtf(var + 1e-5f);
        float dv = sinf(((float)n / (float)N) * 6.28f) * 0.1f;
        out[(size_t)n * HID + c] =
            (x2a - mu) * rstd * g2[c] + be2[c] + dv
            + noise[(size_t)n * HID + c] * 0.05f;
        out[(size_t)n * HID + c + 64] =
            (x2b - mu) * rstd * g2[c + 64] + be2[c + 64] + dv
            + noise[(size_t)n * HID + c + 64] * 0.05f;
    }
}

// classifier: tiled h1 = emb@Wc1 + bc1 -> LN3 -> gelu -> logits
__global__ __launch_bounds__(256) void k_cls(const float* __restrict__ emb,
                                             const float* __restrict__ Wc1,
                                             const float* __restrict__ bc1,
                                             const float* __restrict__ gc,
                                             const float* __restrict__ bec,
                                             const float* __restrict__ Wc2,
                                             const float* __restrict__ bc2,
                                             float* __restrict__ out) {
    __shared__ float et[MT][HID];
    __shared__ float h1t[MT][HID + 1];
    int row0 = blockIdx.x * MT;
    int tid = threadIdx.x;

    for (int idx = tid; idx < MT * HID; idx += 256) {
        int r = idx >> 7, c = idx & 127;
        int row = row0 + r;
        et[r][c] = (row < N) ? emb[(size_t)row * HID + c] : 0.0f;
    }
    __syncthreads();

    {
        int cg = tid & 31, rg = tid >> 5;
        int c0 = cg * 4, r0 = rg * 4;
        float4 b4 = *(const float4*)(bc1 + c0);
        float a00=b4.x,a01=b4.y,a02=b4.z,a03=b4.w;
        float a10=b4.x,a11=b4.y,a12=b4.z,a13=b4.w;
        float a20=b4.x,a21=b4.y,a22=b4.z,a23=b4.w;
        float a30=b4.x,a31=b4.y,a32=b4.z,a33=b4.w;
        for (int k = 0; k < HID; ++k) {
            float4 w = *(const float4*)(Wc1 + (size_t)k * HID + c0);
            float e0 = et[r0 + 0][k], e1 = et[r0 + 1][k];
            float e2 = et[r0 + 2][k], e3 = et[r0 + 3][k];
            a00 += e0*w.x; a01 += e0*w.y; a02 += e0*w.z; a03 += e0*w.w;
            a10 += e1*w.x; a11 += e1*w.y; a12 += e1*w.z; a13 += e1*w.w;
            a20 += e2*w.x; a21 += e2*w.y; a22 += e2*w.z; a23 += e2*w.w;
            a30 += e3*w.x; a31 += e3*w.y; a32 += e3*w.z; a33 += e3*w.w;
        }
        h1t[r0+0][c0+0]=a00; h1t[r0+0][c0+1]=a01; h1t[r0+0][c0+2]=a02; h1t[r0+0][c0+3]=a03;
        h1t[r0+1][c0+0]=a10; h1t[r0+1][c0+1]=a11; h1t[r0+1][c0+2]=a12; h1t[r0+1][c0+3]=a13;
        h1t[r0+2][c0+0]=a20; h1t[r0+2][c0+1]=a21; h1t[r0+2][c0+2]=a22; h1t[r0+2][c0+3]=a23;
        h1t[r0+3][c0+0]=a30; h1t[r0+3][c0+1]=a31; h1t[r0+3][c0+2]=a32; h1t[r0+3][c0+3]=a33;
    }
    __syncthreads();

    // LN3 + gelu: 8 lanes per row (32 rows x 8 = 256 threads)
    {
        int r = tid >> 3, l = tid & 7;
        float p = 0.0f;
        #pragma unroll
        for (int k = 0; k < 16; ++k) p += h1t[r][l + 8 * k];
        #pragma unroll
        for (int m = 1; m < 8; m <<= 1) p += __shfl_xor(p, m);
        float mu = p * (1.0f / HID);
        float v = 0.0f;
        #pragma unroll
        for (int k = 0; k < 16; ++k) { float d = h1t[r][l + 8 * k] - mu; v += d * d; }
        #pragma unroll
        for (int m = 1; m < 8; m <<= 1) v += __shfl_xor(v, m);
        float rstd = rsqrtf(v * (1.0f / HID) + 1e-5f);
        #pragma unroll
        for (int k = 0; k < 16; ++k) {
            int c = l + 8 * k;
            float lnv = (h1t[r][c] - mu) * rstd * gc[c] + bec[c];
            h1t[r][c] = 0.5f * lnv * (1.0f + erff(lnv * 0.70710678118f));
        }
    }
    __syncthreads();

    // logits: 64 outputs (32 rows x 2)
    if (tid < MT * NC) {
        int r = tid >> 1, j = tid & 1;
        int row = row0 + r;
        if (row < N) {
            float acc = bc2[j];
            #pragma unroll 8
            for (int c = 0; c < HID; ++c) acc += h1t[r][c] * Wc2[c * NC + j];
            if (j == 1) acc += sinf((float)row * 0.5f) * 0.2f;
            out[(size_t)N * HID + (size_t)row * NC + j] = acc;
        }
    }
}

extern "C" void kernel_launch(void* const* d_in, const int* in_sizes, int n_in,
                              void* d_out, int out_size, void* d_ws, size_t ws_size,
                              hipStream_t stream) {
    const float* x      = (const float*)d_in[0];
    const int*   ei     = (const int*)d_in[1];
    const float* noise  = (const float*)d_in[2];
    const float* W_proj = (const float*)d_in[3];
    const float* b_proj = (const float*)d_in[4];
    const float* W_gat  = (const float*)d_in[5];
    const float* a_src  = (const float*)d_in[6];
    const float* a_dst  = (const float*)d_in[7];
    const float* b_gat  = (const float*)d_in[8];
    const float* g1     = (const float*)d_in[9];
    const float* be1    = (const float*)d_in[10];
    const float* W_qkv  = (const float*)d_in[11];
    const float* b_qkv  = (const float*)d_in[12];
    const float* W_o    = (const float*)d_in[13];
    const float* b_o    = (const float*)d_in[14];
    const float* g2     = (const float*)d_in[15];
    const float* be2    = (const float*)d_in[16];
    const float* Wc1    = (const float*)d_in[17];
    const float* bc1    = (const float*)d_in[18];
    const float* gc     = (const float*)d_in[19];
    const float* bec    = (const float*)d_in[20];
    const float* Wc2    = (const float*)d_in[21];
    const float* bc2    = (const float*)d_in[22];
    float* out = (float*)d_out;

    float* xh     = (float*)d_ws;                  //  5,120,000
    float* nrm    = xh + 5120000;                  //  5,120,000 (node-major)
    float* a_s    = nrm + 5120000;                 //    320,000
    float* a_d    = a_s + 320000;                  //    320,000
    int*   offs    = (int*)(a_d + 320000);         //     40,008
    int*   cursor  = offs + 40008;                 //     40,000
    int*   csr_src = cursor + 40000;               //  1,320,000
    float* WTq    = (float*)(csr_src + 1320000);   //     49,152
    float* WoT    = WTq + 49152;                   //     16,384
    float* xlastg = WoT + 16384;                   //    640,000

    k_tr<<<(384 * 128 + 128 * 128 + 255) / 256, 256, 0, stream>>>(W_qkv, W_o, WTq, WoT);

    k_pg<<<T * N / MT, 256, 0, stream>>>(x, W_proj, b_proj, W_gat, a_src, a_dst,
                                         xh, a_s, a_d, cursor);

    k_hist<<<T * 8, 256, 0, stream>>>(ei, cursor);
    k_scan<<<T, 256, 0, stream>>>(cursor, offs);
    k_scatter<<<(T * (EN / 4) + 255) / 256, 256, 0, stream>>>(ei, cursor, csr_src);

    k_aggc<<<T * N, 128, 0, stream>>>(offs, csr_src, a_s, a_d, xh,
                                      b_gat, g1, be1, nrm, xlastg);

    k_fuse<<<N / NB, 256, 0, stream>>>(nrm, WTq, b_qkv, xlastg, WoT, b_o,
                                       g2, be2, noise, out);

    k_cls<<<(N + MT - 1) / MT, 256, 0, stream>>>(out, Wc1, bc1, gc, bec, Wc2, bc2, out);
}

// Round 7
// 372.535 us; speedup vs baseline: 1.2453x; 1.0296x over previous
//
#include <hip/hip_runtime.h>
#include <math.h>

#define T 8
#define N 5000
#define E 160000
#define EN (E + N)
#define IN_DIM 64
#define HID 128
#define H 8
#define D 16
#define NC 2
#define MT 32            // rows per tiled-GEMM block
#define NB 4             // nodes per k_fuse block

__device__ __forceinline__ float leaky(float e) { return (e >= 0.0f) ? e : 0.2f * e; }

// fused h=relu(x@Wp+bp); xh=h@Wg; a_s/a_d coef epilogue. Also zeroes cursor.
__global__ __launch_bounds__(256) void k_pg(const float* __restrict__ x,
                                            const float* __restrict__ Wp,
                                            const float* __restrict__ bp,
                                            const float* __restrict__ Wg,
                                            const float* __restrict__ asrc,
                                            const float* __restrict__ adst,
                                            float* __restrict__ xh,
                                            float* __restrict__ a_s,
                                            float* __restrict__ a_d,
                                            int* __restrict__ cursor) {
    __shared__ float xt[MT][IN_DIM];
    __shared__ float ht[MT][HID + 1];
    int row0 = blockIdx.x * MT;
    int tid = threadIdx.x;

    {   // fold the cursor memset into this kernel (runs before k_hist)
        int gi = blockIdx.x * 256 + tid;
        if (gi < T * N) cursor[gi] = 0;
    }

    for (int idx = tid; idx < MT * IN_DIM; idx += 256) {
        int r = idx >> 6, k = idx & 63;
        xt[r][k] = x[(size_t)(row0 + r) * IN_DIM + k];
    }
    __syncthreads();

    int cg = tid & 31;
    int rg = tid >> 5;
    int c0 = cg * 4, r0 = rg * 4;

    {
        float4 b4 = *(const float4*)(bp + c0);
        float a00=b4.x,a01=b4.y,a02=b4.z,a03=b4.w;
        float a10=b4.x,a11=b4.y,a12=b4.z,a13=b4.w;
        float a20=b4.x,a21=b4.y,a22=b4.z,a23=b4.w;
        float a30=b4.x,a31=b4.y,a32=b4.z,a33=b4.w;
        for (int k = 0; k < IN_DIM; ++k) {
            float4 w = *(const float4*)(Wp + (size_t)k * HID + c0);
            float x0 = xt[r0 + 0][k], x1 = xt[r0 + 1][k];
            float x2 = xt[r0 + 2][k], x3 = xt[r0 + 3][k];
            a00 += x0*w.x; a01 += x0*w.y; a02 += x0*w.z; a03 += x0*w.w;
            a10 += x1*w.x; a11 += x1*w.y; a12 += x1*w.z; a13 += x1*w.w;
            a20 += x2*w.x; a21 += x2*w.y; a22 += x2*w.z; a23 += x2*w.w;
            a30 += x3*w.x; a31 += x3*w.y; a32 += x3*w.z; a33 += x3*w.w;
        }
        ht[r0+0][c0+0]=fmaxf(a00,0.f); ht[r0+0][c0+1]=fmaxf(a01,0.f);
        ht[r0+0][c0+2]=fmaxf(a02,0.f); ht[r0+0][c0+3]=fmaxf(a03,0.f);
        ht[r0+1][c0+0]=fmaxf(a10,0.f); ht[r0+1][c0+1]=fmaxf(a11,0.f);
        ht[r0+1][c0+2]=fmaxf(a12,0.f); ht[r0+1][c0+3]=fmaxf(a13,0.f);
        ht[r0+2][c0+0]=fmaxf(a20,0.f); ht[r0+2][c0+1]=fmaxf(a21,0.f);
        ht[r0+2][c0+2]=fmaxf(a22,0.f); ht[r0+2][c0+3]=fmaxf(a23,0.f);
        ht[r0+3][c0+0]=fmaxf(a30,0.f); ht[r0+3][c0+1]=fmaxf(a31,0.f);
        ht[r0+3][c0+2]=fmaxf(a32,0.f); ht[r0+3][c0+3]=fmaxf(a33,0.f);
    }
    __syncthreads();

    float a00=0,a01=0,a02=0,a03=0, a10=0,a11=0,a12=0,a13=0;
    float a20=0,a21=0,a22=0,a23=0, a30=0,a31=0,a32=0,a33=0;
    for (int k = 0; k < HID; ++k) {
        float4 w = *(const float4*)(Wg + (size_t)k * HID + c0);
        float h0 = ht[r0 + 0][k], h1 = ht[r0 + 1][k];
        float h2 = ht[r0 + 2][k], h3 = ht[r0 + 3][k];
        a00 += h0*w.x; a01 += h0*w.y; a02 += h0*w.z; a03 += h0*w.w;
        a10 += h1*w.x; a11 += h1*w.y; a12 += h1*w.z; a13 += h1*w.w;
        a20 += h2*w.x; a21 += h2*w.y; a22 += h2*w.z; a23 += h2*w.w;
        a30 += h3*w.x; a31 += h3*w.y; a32 += h3*w.z; a33 += h3*w.w;
    }
    {
        float4 v;
        v.x=a00; v.y=a01; v.z=a02; v.w=a03;
        *(float4*)(xh + (size_t)(row0 + r0 + 0) * HID + c0) = v;
        v.x=a10; v.y=a11; v.z=a12; v.w=a13;
        *(float4*)(xh + (size_t)(row0 + r0 + 1) * HID + c0) = v;
        v.x=a20; v.y=a21; v.z=a22; v.w=a23;
        *(float4*)(xh + (size_t)(row0 + r0 + 2) * HID + c0) = v;
        v.x=a30; v.y=a31; v.z=a32; v.w=a33;
        *(float4*)(xh + (size_t)(row0 + r0 + 3) * HID + c0) = v;
    }
    __syncthreads();
    ht[r0+0][c0+0]=a00; ht[r0+0][c0+1]=a01; ht[r0+0][c0+2]=a02; ht[r0+0][c0+3]=a03;
    ht[r0+1][c0+0]=a10; ht[r0+1][c0+1]=a11; ht[r0+1][c0+2]=a12; ht[r0+1][c0+3]=a13;
    ht[r0+2][c0+0]=a20; ht[r0+2][c0+1]=a21; ht[r0+2][c0+2]=a22; ht[r0+2][c0+3]=a23;
    ht[r0+3][c0+0]=a30; ht[r0+3][c0+1]=a31; ht[r0+3][c0+2]=a32; ht[r0+3][c0+3]=a33;
    __syncthreads();

    {
        int r = tid >> 3, hh = tid & 7;
        float s1 = 0.0f, s2 = 0.0f;
        #pragma unroll
        for (int d = 0; d < D; ++d) {
            float v = ht[r][hh * D + d];
            s1 += v * asrc[hh * D + d];
            s2 += v * adst[hh * D + d];
        }
        a_s[(size_t)(row0 + r) * H + hh] = s1;
        a_d[(size_t)(row0 + r) * H + hh] = s2;
    }
}

// transpose W_qkv (384x128 -> 128x384) and W_o (128x128 -> 128x128)
__global__ void k_tr(const float* __restrict__ W_qkv, const float* __restrict__ W_o,
                     float* __restrict__ WTq, float* __restrict__ WoT) {
    int idx = blockIdx.x * 256 + threadIdx.x;
    if (idx < 384 * 128) {
        int j = idx >> 7, c = idx & 127;
        WTq[c * 384 + j] = W_qkv[idx];
    } else if (idx < 384 * 128 + 128 * 128) {
        int r = idx - 384 * 128;
        int j = r >> 7, k = r & 127;
        WoT[k * 128 + j] = W_o[r];
    }
}

// LDS-privatized degree histogram: T*8 blocks, each histograms ~EN/8 edges
// of one t into LDS, then flushes 5000 coalesced global atomics.
__global__ __launch_bounds__(256) void k_hist(const int* __restrict__ ei,
                                              int* __restrict__ cursor) {
    __shared__ int hist[N];          // 20 KB
    int t = blockIdx.x >> 3;
    int chunk = blockIdx.x & 7;
    int tid = threadIdx.x;

    for (int i = tid; i < N; i += 256) hist[i] = 0;
    __syncthreads();

    const int CS = (EN + 7) / 8;     // 20625
    int i0 = chunk * CS;
    int i1 = (i0 + CS < EN) ? i0 + CS : EN;
    const int* drow = ei + (size_t)(2 * t + 1) * E;
    for (int i = i0 + tid; i < i1; i += 256) {
        int d = (i < E) ? drow[i] : (i - E);
        atomicAdd(&hist[d], 1);
    }
    __syncthreads();

    int* cur = cursor + t * N;
    for (int i = tid; i < N; i += 256) {
        int c = hist[i];
        if (c) atomicAdd(&cur[i], c);
    }
}

__global__ void k_scan(int* __restrict__ cursor, int* __restrict__ offs) {
    __shared__ int part[256];
    int t = blockIdx.x;
    int tid = threadIdx.x;
    const int CH = 20;
    int begin = tid * CH;
    int sum = 0;
    for (int k = 0; k < CH; ++k) {
        int i = begin + k;
        if (i < N) sum += cursor[t * N + i];
    }
    part[tid] = sum;
    __syncthreads();
    if (tid == 0) {
        int run = 0;
        for (int i = 0; i < 256; ++i) { int v = part[i]; part[i] = run; run += v; }
        offs[t * (N + 1) + N] = run;
    }
    __syncthreads();
    int run = part[tid];
    for (int k = 0; k < CH; ++k) {
        int i = begin + k;
        if (i < N) {
            int cnt = cursor[t * N + i];
            offs[t * (N + 1) + i] = run;
            cursor[t * N + i] = run;
            run += cnt;
        }
    }
}

// scatter with 4-edge ILP per thread (strided within one t for coalescing):
// 4 independent atomic chains per thread hide atomic latency.
__global__ __launch_bounds__(256) void k_scatter(const int* __restrict__ ei,
                                                 int* __restrict__ cursor,
                                                 int* __restrict__ csr_src) {
    const int PT = EN / 4;           // 41250 threads per t
    int idx = blockIdx.x * 256 + threadIdx.x;
    int t = idx / PT;
    if (t >= T) return;
    int e0 = idx - t * PT;

    const int* srow = ei + (size_t)(2 * t) * E;
    const int* drow = srow + E;
    int s[4], d[4];
    #pragma unroll
    for (int j = 0; j < 4; ++j) {
        int i = e0 + j * PT;
        if (i < E) { s[j] = srow[i]; d[j] = drow[i]; }
        else       { s[j] = d[j] = i - E; }
    }
    int* cur = cursor + t * N;
    int p[4];
    #pragma unroll
    for (int j = 0; j < 4; ++j) p[j] = atomicAdd(&cur[d[j]], 1);
    int* csb = csr_src + (size_t)t * EN;
    #pragma unroll
    for (int j = 0; j < 4; ++j) csb[p[j]] = s[j];
}

// GAT aggregation + fused LN1, one block per (dst,t), atomic-free.
// Single-pass softmax. Writes nrm in NODE-MAJOR layout [n][t][c] so the
// downstream fused attention kernel sees 32 contiguous rows per 4 nodes.
__global__ __launch_bounds__(128) void k_aggc(
        const int* __restrict__ offs, const int* __restrict__ csr_src,
        const float* __restrict__ a_s, const float* __restrict__ a_d,
        const float* __restrict__ xh, const float* __restrict__ b_gat,
        const float* __restrict__ g1, const float* __restrict__ be1,
        float* __restrict__ nrm, float* __restrict__ xlast_g) {
    int b = blockIdx.x;
    int t = b & 7;            // T == 8
    int dst = b >> 3;
    int tid = threadIdx.x;

    int o0 = offs[t * (N + 1) + dst];
    int o1 = offs[t * (N + 1) + dst + 1];
    int deg = o1 - o0;
    const int* esrc = csr_src + (size_t)t * EN + o0;
    const float* as_b = a_s + (size_t)t * N * H;
    const float* ad_b = a_d + (size_t)t * N * H;
    const float* xh_b = xh + (size_t)t * N * HID;

    __shared__ float lal[16][H];     // per-tile weights
    __shared__ int   lsrc[16];
    __shared__ float ws_s[2][H];     // per-wave wsum partials
    __shared__ float pacc[2][HID];   // per-wave acc partials
    __shared__ float red[128];

    int eh_e = tid >> 3, eh_h = tid & 7;   // lal-compute mapping
    int el = tid >> 5, cg = tid & 31;      // gather mapping
    int hg = cg >> 2;
    float adh_e = ad_b[dst * H + eh_h];

    float4 acc = {0.0f, 0.0f, 0.0f, 0.0f};
    float wpart = 0.0f;

    int ntile = (deg + 15) >> 4;
    for (int tt = 0; tt < ntile; ++tt) {
        int ej = (tt << 4) + eh_e;
        float w = 0.0f;
        int src = 0;
        if (ej < deg) {
            src = esrc[ej];
            w = expf(leaky(as_b[src * H + eh_h] + adh_e));
        }
        if (eh_h == 0) lsrc[eh_e] = src;
        lal[eh_e][eh_h] = w;
        wpart += w;
        __syncthreads();
        #pragma unroll
        for (int jj = 0; jj < 4; ++jj) {
            int j = (jj << 2) + el;
            int s = lsrc[j];
            float l = lal[j][hg];
            float4 v = *(const float4*)(xh_b + (size_t)s * HID + (cg << 2));
            acc.x += l * v.x; acc.y += l * v.y;
            acc.z += l * v.z; acc.w += l * v.w;
        }
        __syncthreads();
    }

    // reduce wsum over edge-slots
    {
        float w = wpart;
        w += __shfl_xor(w, 8);
        w += __shfl_xor(w, 16);
        w += __shfl_xor(w, 32);
        if ((tid & 63) < 8) ws_s[tid >> 6][eh_h] = w;
    }
    // reduce acc over edge-lanes
    acc.x += __shfl_xor(acc.x, 32);
    acc.y += __shfl_xor(acc.y, 32);
    acc.z += __shfl_xor(acc.z, 32);
    acc.w += __shfl_xor(acc.w, 32);
    if (!(tid & 32)) *(float4*)&pacc[tid >> 6][(tid & 31) << 2] = acc;
    __syncthreads();

    int hh = tid >> 4;
    float wsum = ws_s[0][hh] + ws_s[1][hh];
    float val = (pacc[0][tid] + pacc[1][tid]) / (wsum + 1e-16f);

    // ---- fused LN1 over this (t,dst) row ----
    float v = val + b_gat[tid];
    red[tid] = v;
    __syncthreads();
    if (tid < 64) {
        float s = red[tid] + red[tid + 64];
        #pragma unroll
        for (int m = 1; m < 64; m <<= 1) s += __shfl_xor(s, m);
        if (tid == 0) red[0] = s;
    }
    __syncthreads();
    float mu = red[0] * (1.0f / HID);
    __syncthreads();
    float dv = v - mu;
    red[tid] = dv * dv;
    __syncthreads();
    if (tid < 64) {
        float s = red[tid] + red[tid + 64];
        #pragma unroll
        for (int m = 1; m < 64; m <<= 1) s += __shfl_xor(s, m);
        if (tid == 0) red[0] = s;
    }
    __syncthreads();
    float rstd = rsqrtf(red[0] * (1.0f / HID) + 1e-5f);

    // node-major write
    nrm[(size_t)(dst * T + t) * HID + tid] = dv * rstd * g1[tid] + be1[tid];
    if (t == T - 1) xlast_g[(size_t)dst * HID + tid] = v;
}

// fused qkv GEMM + attention + W_o + LN2 + epilogue for NB=4 nodes/block.
// W_qkv K-chunks staged in LDS (8x fewer L2 weight reads); v accumulators
// never leave registers (PV via partner shfl_xor(32)); q folded into the
// staged K-loop on waves 0-1.
__global__ __launch_bounds__(256) void k_fuse(
        const float* __restrict__ nrm,      // [N*T][HID] node-major
        const float* __restrict__ WTq,      // [128][384]
        const float* __restrict__ b_qkv,
        const float* __restrict__ xlast_g,
        const float* __restrict__ WoT,
        const float* __restrict__ b_o,
        const float* __restrict__ g2, const float* __restrict__ be2,
        const float* __restrict__ noise, float* __restrict__ out) {
    __shared__ float at[NB * T][HID];        // 16 KB; aliased post-GEMM
    __shared__ float kl[NB * T][HID + 4];    // 16.9 KB (stride 132: 16B-aligned rows)
    __shared__ float ql[NB][HID];            // 2 KB
    __shared__ float ws[8][384];             // 12 KB weight stage
    float* attn_s = &at[0][0];               // [NB][H][T] = 256 floats (alias)
    float* ta_s   = &at[0][0] + 256;         // [NB][HID]  = 512 floats (alias)

    int n0 = blockIdx.x * NB;
    int tid = threadIdx.x;
    int cg = tid & 31, rg = tid >> 5;
    int c0 = cg * 4, r0 = rg * 4;

    // load 32 rows of nrm (coalesced float4)
    {
        const float* srcp = nrm + (size_t)n0 * T * HID;
        for (int idx = tid; idx < NB * T * 32; idx += 256) {
            int r = idx >> 5, c4 = (idx & 31) << 2;
            *(float4*)&at[r][c4] = *(const float4*)(srcp + (size_t)r * HID + c4);
        }
    }

    // accumulators (bias-initialized)
    float ka[4][4], va[4][4], qa[4];
    {
        float4 bk = *(const float4*)(b_qkv + 128 + c0);
        float4 bv = *(const float4*)(b_qkv + 256 + c0);
        #pragma unroll
        for (int i = 0; i < 4; ++i) {
            ka[i][0] = bk.x; ka[i][1] = bk.y; ka[i][2] = bk.z; ka[i][3] = bk.w;
            va[i][0] = bv.x; va[i][1] = bv.y; va[i][2] = bv.z; va[i][3] = bv.w;
        }
        if (rg < 4) {
            float4 bq = *(const float4*)(b_qkv + c0);
            qa[0] = bq.x; qa[1] = bq.y; qa[2] = bq.z; qa[3] = bq.w;
        } else {
            qa[0] = qa[1] = qa[2] = qa[3] = 0.0f;
        }
    }
    __syncthreads();

    const float* atq = at[(rg & 3) * T + (T - 1)];  // q source row (waves 0-1)

    for (int kc = 0; kc < 16; ++kc) {
        // stage W rows kc*8..kc*8+7, all 384 cols (unique, coalesced)
        #pragma unroll
        for (int j = 0; j < 3; ++j) {
            int f = j * 256 + tid;           // 0..767 float4 slots
            int row = f / 96;
            int cc = (f - row * 96) << 2;
            *(float4*)&ws[row][cc] =
                *(const float4*)(WTq + (size_t)(kc * 8 + row) * 384 + cc);
        }
        __syncthreads();

        #pragma unroll
        for (int kk = 0; kk < 8; kk += 4) {
            int k = kc * 8 + kk;
            float4 e0 = *(const float4*)&at[r0 + 0][k];
            float4 e1 = *(const float4*)&at[r0 + 1][k];
            float4 e2 = *(const float4*)&at[r0 + 2][k];
            float4 e3 = *(const float4*)&at[r0 + 3][k];
            float e0a[4] = {e0.x, e0.y, e0.z, e0.w};
            float e1a[4] = {e1.x, e1.y, e1.z, e1.w};
            float e2a[4] = {e2.x, e2.y, e2.z, e2.w};
            float e3a[4] = {e3.x, e3.y, e3.z, e3.w};
            float eqa[4] = {0.f, 0.f, 0.f, 0.f};
            if (rg < 4) {
                float4 eq = *(const float4*)&atq[k];
                eqa[0] = eq.x; eqa[1] = eq.y; eqa[2] = eq.z; eqa[3] = eq.w;
            }
            #pragma unroll
            for (int j = 0; j < 4; ++j) {
                float4 wk = *(const float4*)&ws[kk + j][128 + c0];
                float4 wv = *(const float4*)&ws[kk + j][256 + c0];
                float x0 = e0a[j], x1 = e1a[j], x2 = e2a[j], x3 = e3a[j];
                ka[0][0] += x0*wk.x; ka[0][1] += x0*wk.y; ka[0][2] += x0*wk.z; ka[0][3] += x0*wk.w;
                ka[1][0] += x1*wk.x; ka[1][1] += x1*wk.y; ka[1][2] += x1*wk.z; ka[1][3] += x1*wk.w;
                ka[2][0] += x2*wk.x; ka[2][1] += x2*wk.y; ka[2][2] += x2*wk.z; ka[2][3] += x2*wk.w;
                ka[3][0] += x3*wk.x; ka[3][1] += x3*wk.y; ka[3][2] += x3*wk.z; ka[3][3] += x3*wk.w;
                va[0][0] += x0*wv.x; va[0][1] += x0*wv.y; va[0][2] += x0*wv.z; va[0][3] += x0*wv.w;
                va[1][0] += x1*wv.x; va[1][1] += x1*wv.y; va[1][2] += x1*wv.z; va[1][3] += x1*wv.w;
                va[2][0] += x2*wv.x; va[2][1] += x2*wv.y; va[2][2] += x2*wv.z; va[2][3] += x2*wv.w;
                va[3][0] += x3*wv.x; va[3][1] += x3*wv.y; va[3][2] += x3*wv.z; va[3][3] += x3*wv.w;
                if (rg < 4) {
                    float4 wq = *(const float4*)&ws[kk + j][c0];
                    float xq = eqa[j];
                    qa[0] += xq*wq.x; qa[1] += xq*wq.y; qa[2] += xq*wq.z; qa[3] += xq*wq.w;
                }
            }
        }
        __syncthreads();
    }

    // spill k to LDS; q to LDS; v stays in registers
    #pragma unroll
    for (int i = 0; i < 4; ++i) {
        float4 kv4; kv4.x = ka[i][0]; kv4.y = ka[i][1]; kv4.z = ka[i][2]; kv4.w = ka[i][3];
        *(float4*)&kl[r0 + i][c0] = kv4;
    }
    if (rg < 4) {
        float4 q4; q4.x = qa[0]; q4.y = qa[1]; q4.z = qa[2]; q4.w = qa[3];
        *(float4*)&ql[rg][c0] = q4;
    }
    __syncthreads();

    // scores + softmax: thread -> (u, h, tk); softmax over tk = 8-lane shfl.
    // at is dead now; attn_s aliases its first rows.
    {
        int u = tid >> 6, h = (tid >> 3) & 7, tk = tid & 7;
        const float* kr = &kl[u * T + tk][h * D];
        const float* qr = &ql[u][h * D];
        float a = 0.0f;
        #pragma unroll
        for (int d = 0; d < D; ++d) a += qr[d] * kr[d];
        a *= 0.25f;                 // 1/sqrt(D)
        float mx = a;
        mx = fmaxf(mx, __shfl_xor(mx, 1));
        mx = fmaxf(mx, __shfl_xor(mx, 2));
        mx = fmaxf(mx, __shfl_xor(mx, 4));
        float w = expf(a - mx);
        float ssum = w;
        ssum += __shfl_xor(ssum, 1);
        ssum += __shfl_xor(ssum, 2);
        ssum += __shfl_xor(ssum, 4);
        attn_s[u * 64 + h * 8 + tk] = w / ssum;
    }
    __syncthreads();

    // PV from v registers: thread owns (u=rg>>1, tks 4*(rg&1)+0..3, cols c0..c0+3);
    // partner (tid^32) holds the complementary 4 tks of the same (u, cols).
    {
        int u2 = rg >> 1, tkb = (rg & 1) << 2, h2 = cg >> 2;
        const float* ar = attn_s + u2 * 64 + h2 * 8 + tkb;
        float p0 = 0.f, p1 = 0.f, p2 = 0.f, p3 = 0.f;
        #pragma unroll
        for (int i = 0; i < 4; ++i) {
            float av = ar[i];
            p0 += av * va[i][0]; p1 += av * va[i][1];
            p2 += av * va[i][2]; p3 += av * va[i][3];
        }
        p0 += __shfl_xor(p0, 32);
        p1 += __shfl_xor(p1, 32);
        p2 += __shfl_xor(p2, 32);
        p3 += __shfl_xor(p3, 32);
        if (!(tid & 32)) {
            float4 t4; t4.x = p0; t4.y = p1; t4.z = p2; t4.w = p3;
            *(float4*)&ta_s[u2 * 128 + c0] = t4;
        }
    }
    __syncthreads();

    // W_o + residual + LN2 (wave == node, pure shfl) + epilogue
    {
        int u = tid >> 6, c = tid & 63;
        int n = n0 + u;
        float o0 = b_o[c], o1 = b_o[c + 64];
        const float* tar = ta_s + u * 128;
        #pragma unroll 8
        for (int k = 0; k < HID; k += 4) {
            float t0 = tar[k], t1 = tar[k+1], t2 = tar[k+2], t3 = tar[k+3];
            o0 += t0 * WoT[(size_t)(k+0)*128 + c]  + t1 * WoT[(size_t)(k+1)*128 + c]
                + t2 * WoT[(size_t)(k+2)*128 + c]  + t3 * WoT[(size_t)(k+3)*128 + c];
            o1 += t0 * WoT[(size_t)(k+0)*128 + c+64] + t1 * WoT[(size_t)(k+1)*128 + c+64]
                + t2 * WoT[(size_t)(k+2)*128 + c+64] + t3 * WoT[(size_t)(k+3)*128 + c+64];
        }
        float xa = xlast_g[(size_t)n * HID + c];
        float xb = xlast_g[(size_t)n * HID + c + 64];
        float x2a = xa + o0, x2b = xb + o1;
        float s = x2a + x2b, qs = x2a * x2a + x2b * x2b;
        #pragma unroll
        for (int m = 1; m < 64; m <<= 1) {
            s  += __shfl_xor(s, m);
            qs += __shfl_xor(qs, m);
        }
        float mu = s * (1.0f / HID);
        float var = qs * (1.0f / HID) - mu * mu;
        float rstd = rsqrtf(var + 1e-5f);
        float dv = sinf(((float)n / (float)N) * 6.28f) * 0.1f;
        out[(size_t)n * HID + c] =
            (x2a - mu) * rstd * g2[c] + be2[c] + dv
            + noise[(size_t)n * HID + c] * 0.05f;
        out[(size_t)n * HID + c + 64] =
            (x2b - mu) * rstd * g2[c + 64] + be2[c + 64] + dv
            + noise[(size_t)n * HID + c + 64] * 0.05f;
    }
}

// classifier: tiled h1 = emb@Wc1 + bc1 -> LN3 -> gelu -> logits
__global__ __launch_bounds__(256) void k_cls(const float* __restrict__ emb,
                                             const float* __restrict__ Wc1,
                                             const float* __restrict__ bc1,
                                             const float* __restrict__ gc,
                                             const float* __restrict__ bec,
                                             const float* __restrict__ Wc2,
                                             const float* __restrict__ bc2,
                                             float* __restrict__ out) {
    __shared__ float et[MT][HID];
    __shared__ float h1t[MT][HID + 1];
    int row0 = blockIdx.x * MT;
    int tid = threadIdx.x;

    for (int idx = tid; idx < MT * HID; idx += 256) {
        int r = idx >> 7, c = idx & 127;
        int row = row0 + r;
        et[r][c] = (row < N) ? emb[(size_t)row * HID + c] : 0.0f;
    }
    __syncthreads();

    {
        int cg = tid & 31, rg = tid >> 5;
        int c0 = cg * 4, r0 = rg * 4;
        float4 b4 = *(const float4*)(bc1 + c0);
        float a00=b4.x,a01=b4.y,a02=b4.z,a03=b4.w;
        float a10=b4.x,a11=b4.y,a12=b4.z,a13=b4.w;
        float a20=b4.x,a21=b4.y,a22=b4.z,a23=b4.w;
        float a30=b4.x,a31=b4.y,a32=b4.z,a33=b4.w;
        for (int k = 0; k < HID; ++k) {
            float4 w = *(const float4*)(Wc1 + (size_t)k * HID + c0);
            float e0 = et[r0 + 0][k], e1 = et[r0 + 1][k];
            float e2 = et[r0 + 2][k], e3 = et[r0 + 3][k];
            a00 += e0*w.x; a01 += e0*w.y; a02 += e0*w.z; a03 += e0*w.w;
            a10 += e1*w.x; a11 += e1*w.y; a12 += e1*w.z; a13 += e1*w.w;
            a20 += e2*w.x; a21 += e2*w.y; a22 += e2*w.z; a23 += e2*w.w;
            a30 += e3*w.x; a31 += e3*w.y; a32 += e3*w.z; a33 += e3*w.w;
        }
        h1t[r0+0][c0+0]=a00; h1t[r0+0][c0+1]=a01; h1t[r0+0][c0+2]=a02; h1t[r0+0][c0+3]=a03;
        h1t[r0+1][c0+0]=a10; h1t[r0+1][c0+1]=a11; h1t[r0+1][c0+2]=a12; h1t[r0+1][c0+3]=a13;
        h1t[r0+2][c0+0]=a20; h1t[r0+2][c0+1]=a21; h1t[r0+2][c0+2]=a22; h1t[r0+2][c0+3]=a23;
        h1t[r0+3][c0+0]=a30; h1t[r0+3][c0+1]=a31; h1t[r0+3][c0+2]=a32; h1t[r0+3][c0+3]=a33;
    }
    __syncthreads();

    // LN3 + gelu: 8 lanes per row (32 rows x 8 = 256 threads)
    {
        int r = tid >> 3, l = tid & 7;
        float p = 0.0f;
        #pragma unroll
        for (int k = 0; k < 16; ++k) p += h1t[r][l + 8 * k];
        #pragma unroll
        for (int m = 1; m < 8; m <<= 1) p += __shfl_xor(p, m);
        float mu = p * (1.0f / HID);
        float v = 0.0f;
        #pragma unroll
        for (int k = 0; k < 16; ++k) { float d = h1t[r][l + 8 * k] - mu; v += d * d; }
        #pragma unroll
        for (int m = 1; m < 8; m <<= 1) v += __shfl_xor(v, m);
        float rstd = rsqrtf(v * (1.0f / HID) + 1e-5f);
        #pragma unroll
        for (int k = 0; k < 16; ++k) {
            int c = l + 8 * k;
            float lnv = (h1t[r][c] - mu) * rstd * gc[c] + bec[c];
            h1t[r][c] = 0.5f * lnv * (1.0f + erff(lnv * 0.70710678118f));
        }
    }
    __syncthreads();

    // logits: 64 outputs (32 rows x 2)
    if (tid < MT * NC) {
        int r = tid >> 1, j = tid & 1;
        int row = row0 + r;
        if (row < N) {
            float acc = bc2[j];
            #pragma unroll 8
            for (int c = 0; c < HID; ++c) acc += h1t[r][c] * Wc2[c * NC + j];
            if (j == 1) acc += sinf((float)row * 0.5f) * 0.2f;
            out[(size_t)N * HID + (size_t)row * NC + j] = acc;
        }
    }
}

extern "C" void kernel_launch(void* const* d_in, const int* in_sizes, int n_in,
                              void* d_out, int out_size, void* d_ws, size_t ws_size,
                              hipStream_t stream) {
    const float* x      = (const float*)d_in[0];
    const int*   ei     = (const int*)d_in[1];
    const float* noise  = (const float*)d_in[2];
    const float* W_proj = (const float*)d_in[3];
    const float* b_proj = (const float*)d_in[4];
    const float* W_gat  = (const float*)d_in[5];
    const float* a_src  = (const float*)d_in[6];
    const float* a_dst  = (const float*)d_in[7];
    const float* b_gat  = (const float*)d_in[8];
    const float* g1     = (const float*)d_in[9];
    const float* be1    = (const float*)d_in[10];
    const float* W_qkv  = (const float*)d_in[11];
    const float* b_qkv  = (const float*)d_in[12];
    const float* W_o    = (const float*)d_in[13];
    const float* b_o    = (const float*)d_in[14];
    const float* g2     = (const float*)d_in[15];
    const float* be2    = (const float*)d_in[16];
    const float* Wc1    = (const float*)d_in[17];
    const float* bc1    = (const float*)d_in[18];
    const float* gc     = (const float*)d_in[19];
    const float* bec    = (const float*)d_in[20];
    const float* Wc2    = (const float*)d_in[21];
    const float* bc2    = (const float*)d_in[22];
    float* out = (float*)d_out;

    float* xh     = (float*)d_ws;                  //  5,120,000
    float* nrm    = xh + 5120000;                  //  5,120,000 (node-major)
    float* a_s    = nrm + 5120000;                 //    320,000
    float* a_d    = a_s + 320000;                  //    320,000
    int*   offs    = (int*)(a_d + 320000);         //     40,008
    int*   cursor  = offs + 40008;                 //     40,000
    int*   csr_src = cursor + 40000;               //  1,320,000
    float* WTq    = (float*)(csr_src + 1320000);   //     49,152
    float* WoT    = WTq + 49152;                   //     16,384
    float* xlastg = WoT + 16384;                   //    640,000

    k_tr<<<(384 * 128 + 128 * 128 + 255) / 256, 256, 0, stream>>>(W_qkv, W_o, WTq, WoT);

    k_pg<<<T * N / MT, 256, 0, stream>>>(x, W_proj, b_proj, W_gat, a_src, a_dst,
                                         xh, a_s, a_d, cursor);

    k_hist<<<T * 8, 256, 0, stream>>>(ei, cursor);
    k_scan<<<T, 256, 0, stream>>>(cursor, offs);
    k_scatter<<<(T * (EN / 4) + 255) / 256, 256, 0, stream>>>(ei, cursor, csr_src);

    k_aggc<<<T * N, 128, 0, stream>>>(offs, csr_src, a_s, a_d, xh,
                                      b_gat, g1, be1, nrm, xlastg);

    k_fuse<<<N / NB, 256, 0, stream>>>(nrm, WTq, b_qkv, xlastg, WoT, b_o,
                                       g2, be2, noise, out);

    k_cls<<<(N + MT - 1) / MT, 256, 0, stream>>>(out, Wc1, bc1, gc, bec, Wc2, bc2, out);
}